// Round 6
// baseline (1467.962 us; speedup 1.0000x reference)
//
#include <hip/hip_runtime.h>
#include <hip/hip_bf16.h>

// GIN 3-layer forward on MI355X. Round 3 (resubmit x3): CSR gather-reduce replaces atomic scatter.
// Per launch: build CSR (deg count -> 2-level scan -> fill), then per layer:
//   B = h_in + gather-sum over CSR          (agg_csr_k, no atomics)
//   C = relu(B@W0+b0); C = relu(C@W1+b1) in-place; B = C@W2+b2
//   stats = colsum/colsumsq(B); Hb = BN(B)*gamma+beta (+relu l<2)
//   hout (+)= Hb @ linW[l]
// logits = hout @ clsW + clsB

// ---------------- CSR build ----------------

__global__ void zero_int_k(int* __restrict__ p, int n) {
    int i = blockIdx.x * blockDim.x + threadIdx.x;
    if (i < n) p[i] = 0;
}

__global__ void deg_count_k(const int* __restrict__ dst, int* __restrict__ deg, int E) {
    int e = blockIdx.x * blockDim.x + threadIdx.x;
    if (e < E) atomicAdd(&deg[dst[e]], 1);
}

// chunkSum[b] = sum of deg[b*512 .. b*512+511]
__global__ __launch_bounds__(512) void chunk_reduce_k(const int* __restrict__ deg,
                                                      int* __restrict__ chunkSum, int N) {
    __shared__ int s[512];
    int i = blockIdx.x * 512 + threadIdx.x;
    s[threadIdx.x] = (i < N) ? deg[i] : 0;
    __syncthreads();
    for (int off = 256; off > 0; off >>= 1) {
        if (threadIdx.x < off) s[threadIdx.x] += s[threadIdx.x + off];
        __syncthreads();
    }
    if (threadIdx.x == 0) chunkSum[blockIdx.x] = s[0];
}

// serial exclusive scan of chunk sums (nchunks ~ 98); writes rowPtr[N] = total
__global__ void scan_chunks_k(int* __restrict__ chunkSum, int* __restrict__ rowPtr,
                              int nchunks, int N) {
    if (threadIdx.x == 0 && blockIdx.x == 0) {
        int run = 0;
        for (int b = 0; b < nchunks; b++) {
            int v = chunkSum[b];
            chunkSum[b] = run;   // becomes exclusive chunk offset
            run += v;
        }
        rowPtr[N] = run;
    }
}

// per-chunk exclusive scan + chunk offset -> rowPtr, cursor
__global__ __launch_bounds__(512) void expand_scan_k(const int* __restrict__ deg,
                                                     const int* __restrict__ chunkOff,
                                                     int* __restrict__ rowPtr,
                                                     int* __restrict__ cursor, int N) {
    __shared__ int s[512];
    const int t = threadIdx.x;
    const int i = blockIdx.x * 512 + t;
    const int v = (i < N) ? deg[i] : 0;
    s[t] = v;
    __syncthreads();
    for (int off = 1; off < 512; off <<= 1) {
        int u = (t >= off) ? s[t - off] : 0;
        __syncthreads();
        s[t] += u;
        __syncthreads();
    }
    if (i < N) {
        int excl = s[t] - v + chunkOff[blockIdx.x];
        rowPtr[i] = excl;
        cursor[i] = excl;
    }
}

__global__ void fill_k(const int* __restrict__ src, const int* __restrict__ dst,
                       int* __restrict__ cursor, int* __restrict__ sortedSrc, int E) {
    int e = blockIdx.x * blockDim.x + threadIdx.x;
    if (e < E) {
        int pos = atomicAdd(&cursor[dst[e]], 1);
        sortedSrc[pos] = src[e];
    }
}

// ---------------- aggregation: B[i] = h[i] + sum_{j in row i} h[sortedSrc[j]] ----------------
// 32 lanes per node, float4 per lane; 8 nodes per 256-thread block.
__global__ __launch_bounds__(256) void agg_csr_k(const float* __restrict__ h,
                                                 const int* __restrict__ sortedSrc,
                                                 const int* __restrict__ rowPtr,
                                                 float* __restrict__ B, int N) {
    const int node = blockIdx.x * 8 + (threadIdx.x >> 5);
    if (node >= N) return;
    const int f = threadIdx.x & 31;
    const float4* h4 = (const float4*)h;
    float4 acc = h4[(size_t)node * 32 + f];
    const int beg = rowPtr[node], end = rowPtr[node + 1];
    for (int j = beg; j < end; j++) {
        int s = sortedSrc[j];
        float4 v = h4[(size_t)s * 32 + f];
        acc.x += v.x; acc.y += v.y; acc.z += v.z; acc.w += v.w;
    }
    ((float4*)B)[(size_t)node * 32 + f] = acc;
}

// ---------------- GEMM: out[N,NCOLS] = A[N,128]@W[128,NCOLS] (+bias)(relu)(+=out) ----------------
template <int NCOLS, bool RELU, bool ACCUM>
__global__ __launch_bounds__(256) void gemm_k(const float* __restrict__ A,
                                              const float* __restrict__ W,
                                              const float* __restrict__ bias,
                                              float* __restrict__ out, int N) {
    constexpr int CG = NCOLS / 4;
    constexpr int RG = 256 / CG;
    constexpr int TM = RG * 8;
    __shared__ float sA[TM * 128];
    __shared__ float sW[128 * NCOLS];
    const int t = threadIdx.x;
    const int row0 = blockIdx.x * TM;

    for (int i = t; i < 128 * NCOLS / 4; i += 256)
        ((float4*)sW)[i] = ((const float4*)W)[i];
    for (int i = t; i < TM * 32; i += 256) {
        int r = row0 + (i >> 5);
        float4 v = {0.f, 0.f, 0.f, 0.f};
        if (r < N) v = ((const float4*)A)[(size_t)r * 32 + (i & 31)];
        ((float4*)sA)[i] = v;
    }
    __syncthreads();

    const int cg = t % CG, rg = t / CG;
    const int c0 = cg * 4;
    float acc[8][4];
#pragma unroll
    for (int i = 0; i < 8; i++)
        acc[i][0] = acc[i][1] = acc[i][2] = acc[i][3] = 0.f;
    const float* sa = sA + rg * 8 * 128;

#pragma unroll 4
    for (int k = 0; k < 128; k += 4) {
        float4 b0 = *(const float4*)&sW[(k + 0) * NCOLS + c0];
        float4 b1 = *(const float4*)&sW[(k + 1) * NCOLS + c0];
        float4 b2 = *(const float4*)&sW[(k + 2) * NCOLS + c0];
        float4 b3 = *(const float4*)&sW[(k + 3) * NCOLS + c0];
#pragma unroll
        for (int i = 0; i < 8; i++) {
            float4 a = *(const float4*)&sa[i * 128 + k];
            acc[i][0] += a.x * b0.x + a.y * b1.x + a.z * b2.x + a.w * b3.x;
            acc[i][1] += a.x * b0.y + a.y * b1.y + a.z * b2.y + a.w * b3.y;
            acc[i][2] += a.x * b0.z + a.y * b1.z + a.z * b2.z + a.w * b3.z;
            acc[i][3] += a.x * b0.w + a.y * b1.w + a.z * b2.w + a.w * b3.w;
        }
    }

    float4 bv = {0.f, 0.f, 0.f, 0.f};
    if (bias) bv = *(const float4*)&bias[c0];
#pragma unroll
    for (int i = 0; i < 8; i++) {
        int r = row0 + rg * 8 + i;
        if (r >= N) break;
        float* po = out + (size_t)r * NCOLS + c0;
        float4 o;
        o.x = acc[i][0] + bv.x;
        o.y = acc[i][1] + bv.y;
        o.z = acc[i][2] + bv.z;
        o.w = acc[i][3] + bv.w;
        if (ACCUM) {
            float4 e = *(const float4*)po;
            o.x += e.x; o.y += e.y; o.z += e.z; o.w += e.w;
        }
        if (RELU) {
            o.x = fmaxf(o.x, 0.f); o.y = fmaxf(o.y, 0.f);
            o.z = fmaxf(o.z, 0.f); o.w = fmaxf(o.w, 0.f);
        }
        *(float4*)po = o;
    }
}

// ---------------- BatchNorm ----------------

__global__ void zero_f_k(float* __restrict__ p, int n) {
    int i = blockIdx.x * blockDim.x + threadIdx.x;
    if (i < n) p[i] = 0.f;
}

__global__ __launch_bounds__(256) void bn_partial_k(const float* __restrict__ Z,
                                                    float* __restrict__ stats, int N) {
    const int t = threadIdx.x;
    const int c = t & 127, sub = t >> 7;
    const int base = blockIdx.x * 256;
    const int rend = min(N, base + 256);
    float s = 0.f, s2 = 0.f;
    for (int r = base + sub; r < rend; r += 2) {
        float v = Z[(size_t)r * 128 + c];
        s += v;
        s2 += v * v;
    }
    atomicAdd(&stats[c], s);
    atomicAdd(&stats[128 + c], s2);
}

__global__ void bn_apply_k(const float* __restrict__ Z, const float* __restrict__ stats,
                           const float* __restrict__ gamma, const float* __restrict__ beta,
                           float* __restrict__ out, int N, int relu) {
    size_t i = (size_t)blockIdx.x * blockDim.x + threadIdx.x;
    const size_t total = (size_t)N * 32;
    const size_t stride = (size_t)gridDim.x * blockDim.x;
    const float inv = 1.f / (float)N;
    for (; i < total; i += stride) {
        int c0 = (int)(i & 31) * 4;
        float4 z = ((const float4*)Z)[i];
        float o[4] = {z.x, z.y, z.z, z.w};
#pragma unroll
        for (int j = 0; j < 4; j++) {
            int c = c0 + j;
            float mean = stats[c] * inv;
            float var = stats[128 + c] * inv - mean * mean;
            float rstd = rsqrtf(var + 1e-5f);
            float v = (o[j] - mean) * rstd * gamma[c] + beta[c];
            if (relu) v = fmaxf(v, 0.f);
            o[j] = v;
        }
        float4 ov = {o[0], o[1], o[2], o[3]};
        ((float4*)out)[i] = ov;
    }
}

// ---------------- launch ----------------

extern "C" void kernel_launch(void* const* d_in, const int* in_sizes, int n_in,
                              void* d_out, int out_size, void* d_ws, size_t ws_size,
                              hipStream_t stream) {
    const float* x     = (const float*)d_in[0];
    const int*   ei    = (const int*)d_in[1];
    const float* convW = (const float*)d_in[2];
    const float* convB = (const float*)d_in[3];
    const float* gamma = (const float*)d_in[4];
    const float* beta  = (const float*)d_in[5];
    const float* linW  = (const float*)d_in[6];
    const float* linB  = (const float*)d_in[7];
    const float* clsW  = (const float*)d_in[8];
    const float* clsB  = (const float*)d_in[9];

    const int N = in_sizes[0] / 128;   // 50000
    const int E = in_sizes[1] / 2;     // 800000
    const int* src = ei;
    const int* dst = ei + E;

    float* B     = (float*)d_ws;
    float* C     = B + (size_t)N * 128;
    float* Hb    = C + (size_t)N * 128;
    float* stats = Hb + (size_t)N * 128;
    int* deg       = (int*)(stats + 256);
    int* rowPtr    = deg + N;
    int* cursor    = rowPtr + (N + 1);
    int* chunkSum  = cursor + N;
    int* sortedSrc = chunkSum + 512;

    float* logits = (float*)d_out;
    float* hout   = (float*)d_out + (size_t)N * 64;

    const int nchunks = (N + 511) / 512;
    const int eb = (E + 255) / 256;

    // ---- CSR build (once; graph constant across layers) ----
    zero_int_k<<<(N + 255) / 256, 256, 0, stream>>>(deg, N);
    deg_count_k<<<eb, 256, 0, stream>>>(dst, deg, E);
    chunk_reduce_k<<<nchunks, 512, 0, stream>>>(deg, chunkSum, N);
    scan_chunks_k<<<1, 64, 0, stream>>>(chunkSum, rowPtr, nchunks, N);
    expand_scan_k<<<nchunks, 512, 0, stream>>>(deg, chunkSum, rowPtr, cursor, N);
    fill_k<<<eb, 256, 0, stream>>>(src, dst, cursor, sortedSrc, E);

    const int nb128 = (N + 63) / 64;
    const int aggb = (N + 7) / 8;

    const float* hin = x;
    for (int l = 0; l < 3; l++) {
        agg_csr_k<<<aggb, 256, 0, stream>>>(hin, sortedSrc, rowPtr, B, N);

        const float* W0 = convW + ((size_t)l * 3 + 0) * 128 * 128;
        const float* W1 = convW + ((size_t)l * 3 + 1) * 128 * 128;
        const float* W2 = convW + ((size_t)l * 3 + 2) * 128 * 128;
        const float* b0 = convB + ((size_t)l * 3 + 0) * 128;
        const float* b1 = convB + ((size_t)l * 3 + 1) * 128;
        const float* b2 = convB + ((size_t)l * 3 + 2) * 128;

        gemm_k<128, true,  false><<<nb128, 256, 0, stream>>>(B, W0, b0, C, N);
        gemm_k<128, true,  false><<<nb128, 256, 0, stream>>>(C, W1, b1, C, N); // in-place safe
        gemm_k<128, false, false><<<nb128, 256, 0, stream>>>(C, W2, b2, B, N);

        zero_f_k<<<1, 256, 0, stream>>>(stats, 256);
        bn_partial_k<<<(N + 255) / 256, 256, 0, stream>>>(B, stats, N);
        bn_apply_k<<<2048, 256, 0, stream>>>(B, stats, gamma + l * 128, beta + l * 128,
                                             Hb, N, l < 2 ? 1 : 0);

        if (l == 0)
            gemm_k<128, false, false><<<nb128, 256, 0, stream>>>(Hb, linW, linB, hout, N);
        else
            gemm_k<128, false, true><<<nb128, 256, 0, stream>>>(
                Hb, linW + (size_t)l * 128 * 128, nullptr, hout, N);

        hin = Hb;
    }

    const int nb64 = (N + 127) / 128;
    gemm_k<64, false, false><<<nb64, 256, 0, stream>>>(hout, clsW, clsB, logits, N);
}

// Round 10
// 820.555 us; speedup vs baseline: 1.7890x; 1.7890x over previous
//
#include <hip/hip_runtime.h>
#include <hip/hip_bf16.h>
#include <stdint.h>

// GIN 3-layer forward on MI355X. Round 7 (resubmit x3): bf16-MFMA GEMMs (16x16x32), CSR agg unchanged.
// Per launch: CSR build + weight transpose->bf16, then per layer:
//   B = h_in + gather-sum over CSR          (agg_csr_k, fp32, validated)
//   C = relu(B@W0+b0); C = relu(C@W1+b1) in-place; B = C@W2+b2   (MFMA)
//   stats; Hb = BN(B)*gamma+beta (+relu l<2)                      (validated)
//   hout (+)= Hb @ linW[l]                                        (MFMA)
// logits = hout @ clsW + clsB                                     (MFMA, N=64)

using bf16x8 = __attribute__((ext_vector_type(8))) short;
using f32x4  = __attribute__((ext_vector_type(4))) float;

__device__ inline short f2bf(float f) {
    union { __hip_bfloat16 h; short s; } u;
    u.h = __float2bfloat16(f);
    return u.s;
}

// ---------------- CSR build (unchanged, validated) ----------------

__global__ void zero_int_k(int* __restrict__ p, int n) {
    int i = blockIdx.x * blockDim.x + threadIdx.x;
    if (i < n) p[i] = 0;
}

__global__ void deg_count_k(const int* __restrict__ dst, int* __restrict__ deg, int E) {
    int e = blockIdx.x * blockDim.x + threadIdx.x;
    if (e < E) atomicAdd(&deg[dst[e]], 1);
}

__global__ __launch_bounds__(512) void chunk_reduce_k(const int* __restrict__ deg,
                                                      int* __restrict__ chunkSum, int N) {
    __shared__ int s[512];
    int i = blockIdx.x * 512 + threadIdx.x;
    s[threadIdx.x] = (i < N) ? deg[i] : 0;
    __syncthreads();
    for (int off = 256; off > 0; off >>= 1) {
        if (threadIdx.x < off) s[threadIdx.x] += s[threadIdx.x + off];
        __syncthreads();
    }
    if (threadIdx.x == 0) chunkSum[blockIdx.x] = s[0];
}

__global__ void scan_chunks_k(int* __restrict__ chunkSum, int* __restrict__ rowPtr,
                              int nchunks, int N) {
    if (threadIdx.x == 0 && blockIdx.x == 0) {
        int run = 0;
        for (int b = 0; b < nchunks; b++) {
            int v = chunkSum[b];
            chunkSum[b] = run;
            run += v;
        }
        rowPtr[N] = run;
    }
}

__global__ __launch_bounds__(512) void expand_scan_k(const int* __restrict__ deg,
                                                     const int* __restrict__ chunkOff,
                                                     int* __restrict__ rowPtr,
                                                     int* __restrict__ cursor, int N) {
    __shared__ int s[512];
    const int t = threadIdx.x;
    const int i = blockIdx.x * 512 + t;
    const int v = (i < N) ? deg[i] : 0;
    s[t] = v;
    __syncthreads();
    for (int off = 1; off < 512; off <<= 1) {
        int u = (t >= off) ? s[t - off] : 0;
        __syncthreads();
        s[t] += u;
        __syncthreads();
    }
    if (i < N) {
        int excl = s[t] - v + chunkOff[blockIdx.x];
        rowPtr[i] = excl;
        cursor[i] = excl;
    }
}

__global__ void fill_k(const int* __restrict__ src, const int* __restrict__ dst,
                       int* __restrict__ cursor, int* __restrict__ sortedSrc, int E) {
    int e = blockIdx.x * blockDim.x + threadIdx.x;
    if (e < E) {
        int pos = atomicAdd(&cursor[dst[e]], 1);
        sortedSrc[pos] = src[e];
    }
}

// ---------------- aggregation (unchanged, validated) ----------------

__global__ __launch_bounds__(256) void agg_csr_k(const float* __restrict__ h,
                                                 const int* __restrict__ sortedSrc,
                                                 const int* __restrict__ rowPtr,
                                                 float* __restrict__ B, int N) {
    const int node = blockIdx.x * 8 + (threadIdx.x >> 5);
    if (node >= N) return;
    const int f = threadIdx.x & 31;
    const float4* h4 = (const float4*)h;
    float4 acc = h4[(size_t)node * 32 + f];
    const int beg = rowPtr[node], end = rowPtr[node + 1];
    for (int j = beg; j < end; j++) {
        int s = sortedSrc[j];
        float4 v = h4[(size_t)s * 32 + f];
        acc.x += v.x; acc.y += v.y; acc.z += v.z; acc.w += v.w;
    }
    ((float4*)B)[(size_t)node * 32 + f] = acc;
}

// ---------------- weight transpose + fp32->bf16 (once per launch) ----------------
// 13 blocks: 0-8 convW (128x128), 9-11 linW slices (128x128), 12 clsW (128x64).
// dst slot b: Wt + b*16384 shorts, layout [n][k] (n = out col, k = 0..127).
__global__ __launch_bounds__(256) void transpose_w_k(const float* __restrict__ convW,
                                                     const float* __restrict__ linW,
                                                     const float* __restrict__ clsW,
                                                     short* __restrict__ Wt) {
    const int b = blockIdx.x;
    const float* src;
    int NC;
    if (b < 9)       { src = convW + (size_t)b * 16384;      NC = 128; }
    else if (b < 12) { src = linW + (size_t)(b - 9) * 16384; NC = 128; }
    else             { src = clsW;                            NC = 64; }
    short* dst = Wt + (size_t)b * 16384;
    const int tot = NC * 32;                 // n-major, k chunks of 4
    for (int i = threadIdx.x; i < tot; i += 256) {
        int n = i >> 5, k0 = (i & 31) << 2;
        short4 s;
        s.x = f2bf(src[(k0 + 0) * NC + n]);
        s.y = f2bf(src[(k0 + 1) * NC + n]);
        s.z = f2bf(src[(k0 + 2) * NC + n]);
        s.w = f2bf(src[(k0 + 3) * NC + n]);
        *(short4*)&dst[n * 128 + k0] = s;
    }
}

// ---------------- bf16 MFMA GEMM: out[N,NCOLS] = A[N,128] @ W (+bias)(relu)(+=out) ----------------
// BM=64 rows/block, 4 waves, 16 rows/wave. Wt is bf16 [NCOLS][128].
// Fragment layout (m89/m201-verified): A lane=row(l&15),k=(l>>4)*8+e; D row=(l>>4)*4+j,col=l&15.
template <int NCOLS, bool RELU, bool ACCUM, bool BIAS>
__global__ __launch_bounds__(256) void mfma_gemm_k(const float* __restrict__ A,
                                                   const short* __restrict__ Wt,
                                                   const float* __restrict__ bias,
                                                   float* __restrict__ out, int N) {
    constexpr int NT = NCOLS / 16;           // 16x16 col tiles
    constexpr int LR = 136;                  // LDS row pitch in halves (272B, pad kills conflicts)
    __shared__ __align__(16) short sA[64 * LR];
    __shared__ __align__(16) short sW[NCOLS * LR];
    const int t = threadIdx.x;
    const int row0 = blockIdx.x * 64;

    // stage Wt (bf16 global, coalesced 16B) -> sW[n][k]
    for (int i = t; i < NCOLS * 16; i += 256) {
        int n = i >> 4, k0 = (i & 15) << 3;
        *(bf16x8*)&sW[n * LR + k0] = *(const bf16x8*)&Wt[n * 128 + k0];
    }
    // stage A (fp32 global, coalesced 16B) -> bf16 sA[r][k]
    for (int i = t; i < 64 * 32; i += 256) {
        int r = i >> 5, c0 = (i & 31) << 2;
        int gr = row0 + r;
        float4 v = {0.f, 0.f, 0.f, 0.f};
        if (gr < N) v = ((const float4*)A)[(size_t)gr * 32 + (c0 >> 2)];
        short4 s = {f2bf(v.x), f2bf(v.y), f2bf(v.z), f2bf(v.w)};
        *(short4*)&sA[r * LR + c0] = s;
    }
    __syncthreads();

    const int w = t >> 6, l = t & 63;
    const int lr = l & 15, lg = l >> 4;

    bf16x8 af[4];
#pragma unroll
    for (int kb = 0; kb < 4; kb++)
        af[kb] = *(const bf16x8*)&sA[(w * 16 + lr) * LR + kb * 32 + lg * 8];

    f32x4 acc[NT];
#pragma unroll
    for (int n = 0; n < NT; n++) acc[n] = {0.f, 0.f, 0.f, 0.f};

#pragma unroll
    for (int n = 0; n < NT; n++) {
#pragma unroll
        for (int kb = 0; kb < 4; kb++) {
            bf16x8 bf = *(const bf16x8*)&sW[(n * 16 + lr) * LR + kb * 32 + lg * 8];
            acc[n] = __builtin_amdgcn_mfma_f32_16x16x32_bf16(af[kb], bf, acc[n], 0, 0, 0);
        }
    }

#pragma unroll
    for (int n = 0; n < NT; n++) {
        const int col = n * 16 + lr;
        float bv = 0.f;
        if (BIAS) bv = bias[col];
#pragma unroll
        for (int j = 0; j < 4; j++) {
            int r = row0 + w * 16 + lg * 4 + j;
            if (r < N) {
                float v = acc[n][j] + bv;
                float* p = out + (size_t)r * NCOLS + col;
                if (ACCUM) v += *p;
                if (RELU) v = fmaxf(v, 0.f);
                *p = v;
            }
        }
    }
}

// ---------------- BatchNorm (unchanged, validated) ----------------

__global__ void zero_f_k(float* __restrict__ p, int n) {
    int i = blockIdx.x * blockDim.x + threadIdx.x;
    if (i < n) p[i] = 0.f;
}

__global__ __launch_bounds__(256) void bn_partial_k(const float* __restrict__ Z,
                                                    float* __restrict__ stats, int N) {
    const int t = threadIdx.x;
    const int c = t & 127, sub = t >> 7;
    const int base = blockIdx.x * 256;
    const int rend = min(N, base + 256);
    float s = 0.f, s2 = 0.f;
    for (int r = base + sub; r < rend; r += 2) {
        float v = Z[(size_t)r * 128 + c];
        s += v;
        s2 += v * v;
    }
    atomicAdd(&stats[c], s);
    atomicAdd(&stats[128 + c], s2);
}

__global__ void bn_apply_k(const float* __restrict__ Z, const float* __restrict__ stats,
                           const float* __restrict__ gamma, const float* __restrict__ beta,
                           float* __restrict__ out, int N, int relu) {
    size_t i = (size_t)blockIdx.x * blockDim.x + threadIdx.x;
    const size_t total = (size_t)N * 32;
    const size_t stride = (size_t)gridDim.x * blockDim.x;
    const float inv = 1.f / (float)N;
    for (; i < total; i += stride) {
        int c0 = (int)(i & 31) * 4;
        float4 z = ((const float4*)Z)[i];
        float o[4] = {z.x, z.y, z.z, z.w};
#pragma unroll
        for (int j = 0; j < 4; j++) {
            int c = c0 + j;
            float mean = stats[c] * inv;
            float var = stats[128 + c] * inv - mean * mean;
            float rstd = rsqrtf(var + 1e-5f);
            float v = (o[j] - mean) * rstd * gamma[c] + beta[c];
            if (relu) v = fmaxf(v, 0.f);
            o[j] = v;
        }
        float4 ov = {o[0], o[1], o[2], o[3]};
        ((float4*)out)[i] = ov;
    }
}

// ---------------- launch ----------------

extern "C" void kernel_launch(void* const* d_in, const int* in_sizes, int n_in,
                              void* d_out, int out_size, void* d_ws, size_t ws_size,
                              hipStream_t stream) {
    const float* x     = (const float*)d_in[0];
    const int*   ei    = (const int*)d_in[1];
    const float* convW = (const float*)d_in[2];
    const float* convB = (const float*)d_in[3];
    const float* gamma = (const float*)d_in[4];
    const float* beta  = (const float*)d_in[5];
    const float* linW  = (const float*)d_in[6];
    const float* linB  = (const float*)d_in[7];
    const float* clsW  = (const float*)d_in[8];
    const float* clsB  = (const float*)d_in[9];

    const int N = in_sizes[0] / 128;   // 50000
    const int E = in_sizes[1] / 2;     // 800000
    const int* src = ei;
    const int* dst = ei + E;

    float* B     = (float*)d_ws;
    float* C     = B + (size_t)N * 128;
    float* Hb    = C + (size_t)N * 128;
    float* stats = Hb + (size_t)N * 128;
    int* deg       = (int*)(stats + 256);
    int* rowPtr    = deg + N;
    int* cursor    = rowPtr + (N + 1);
    int* chunkSum  = cursor + N;
    int* sortedSrc = chunkSum + 512;
    short* Wt = (short*)((((uintptr_t)(sortedSrc + E)) + 15) & ~(uintptr_t)15);

    float* logits = (float*)d_out;
    float* hout   = (float*)d_out + (size_t)N * 64;

    const int nchunks = (N + 511) / 512;
    const int eb = (E + 255) / 256;

    // ---- CSR build (graph constant across layers) ----
    zero_int_k<<<(N + 255) / 256, 256, 0, stream>>>(deg, N);
    deg_count_k<<<eb, 256, 0, stream>>>(dst, deg, E);
    chunk_reduce_k<<<nchunks, 512, 0, stream>>>(deg, chunkSum, N);
    scan_chunks_k<<<1, 64, 0, stream>>>(chunkSum, rowPtr, nchunks, N);
    expand_scan_k<<<nchunks, 512, 0, stream>>>(deg, chunkSum, rowPtr, cursor, N);
    fill_k<<<eb, 256, 0, stream>>>(src, dst, cursor, sortedSrc, E);

    // ---- weights -> bf16 transposed, once ----
    transpose_w_k<<<13, 256, 0, stream>>>(convW, linW, clsW, Wt);

    const int nbm = (N + 63) / 64;
    const int aggb = (N + 7) / 8;

    const float* hin = x;
    for (int l = 0; l < 3; l++) {
        agg_csr_k<<<aggb, 256, 0, stream>>>(hin, sortedSrc, rowPtr, B, N);

        const short* Wt0 = Wt + (size_t)(l * 3 + 0) * 16384;
        const short* Wt1 = Wt + (size_t)(l * 3 + 1) * 16384;
        const short* Wt2 = Wt + (size_t)(l * 3 + 2) * 16384;
        const float* b0 = convB + ((size_t)l * 3 + 0) * 128;
        const float* b1 = convB + ((size_t)l * 3 + 1) * 128;
        const float* b2 = convB + ((size_t)l * 3 + 2) * 128;

        mfma_gemm_k<128, true,  false, true><<<nbm, 256, 0, stream>>>(B, Wt0, b0, C, N);
        mfma_gemm_k<128, true,  false, true><<<nbm, 256, 0, stream>>>(C, Wt1, b1, C, N);
        mfma_gemm_k<128, false, false, true><<<nbm, 256, 0, stream>>>(C, Wt2, b2, B, N);

        zero_f_k<<<1, 256, 0, stream>>>(stats, 256);
        bn_partial_k<<<(N + 255) / 256, 256, 0, stream>>>(B, stats, N);
        bn_apply_k<<<2048, 256, 0, stream>>>(B, stats, gamma + l * 128, beta + l * 128,
                                             Hb, N, l < 2 ? 1 : 0);

        const short* WtL = Wt + (size_t)(9 + l) * 16384;
        if (l == 0)
            mfma_gemm_k<128, false, false, true><<<nbm, 256, 0, stream>>>(Hb, WtL, linB, hout, N);
        else
            mfma_gemm_k<128, false, true, false><<<nbm, 256, 0, stream>>>(Hb, WtL, nullptr, hout, N);

        hin = Hb;
    }

    const short* WtC = Wt + (size_t)12 * 16384;
    mfma_gemm_k<64, false, false, true><<<nbm, 256, 0, stream>>>(hout, WtC, clsB, logits, N);
}

// Round 11
// 650.702 us; speedup vs baseline: 2.2560x; 1.2610x over previous
//
#include <hip/hip_runtime.h>
#include <hip/hip_bf16.h>
#include <stdint.h>

// GIN 3-layer forward on MI355X. Round 11: bf16 intermediates everywhere,
// BN-stats fused into W2-GEMM epilogue, single fused concat-lin+cls kernel.
// Per launch: CSR build + weight transpose->bf16 + x->bf16, then per layer:
//   B16 = h16 + gather-sum (agg16_k, bf16 in/out, fp32 acc)
//   C16 = relu(B16@W0+b0); C16 = relu(C16@W1+b1) in-place    (MFMA, bf16 out)
//   Z fp32 = C16@W2+b2, col sums/sumsq -> stats (fused)       (MFMA)
//   H16[l] = BN(Z)*gamma+beta (+relu l<2), bf16
// fuse3_k: h = [H1|H2|H3]@linW+linB -> hout fp32; logits = h@clsW+clsB.
// Aliasing: B16 = (short*)Z (lifetimes disjoint). C16 doubles as x16.

using bf16x8 = __attribute__((ext_vector_type(8))) short;
using f32x4  = __attribute__((ext_vector_type(4))) float;

__device__ inline short f2bf(float f) {
    union { __hip_bfloat16 h; short s; } u;
    u.h = __float2bfloat16(f);
    return u.s;
}
__device__ inline float bf2f(short s) {
    union { uint32_t u; float f; } c;
    c.u = ((uint32_t)(uint16_t)s) << 16;
    return c.f;
}

// ---------------- CSR build (unchanged, validated) ----------------

__global__ void zero_int_k(int* __restrict__ p, int n) {
    int i = blockIdx.x * blockDim.x + threadIdx.x;
    if (i < n) p[i] = 0;
}

__global__ void deg_count_k(const int* __restrict__ dst, int* __restrict__ deg, int E) {
    int e = blockIdx.x * blockDim.x + threadIdx.x;
    if (e < E) atomicAdd(&deg[dst[e]], 1);
}

__global__ __launch_bounds__(512) void chunk_reduce_k(const int* __restrict__ deg,
                                                      int* __restrict__ chunkSum, int N) {
    __shared__ int s[512];
    int i = blockIdx.x * 512 + threadIdx.x;
    s[threadIdx.x] = (i < N) ? deg[i] : 0;
    __syncthreads();
    for (int off = 256; off > 0; off >>= 1) {
        if (threadIdx.x < off) s[threadIdx.x] += s[threadIdx.x + off];
        __syncthreads();
    }
    if (threadIdx.x == 0) chunkSum[blockIdx.x] = s[0];
}

__global__ void scan_chunks_k(int* __restrict__ chunkSum, int* __restrict__ rowPtr,
                              int nchunks, int N) {
    if (threadIdx.x == 0 && blockIdx.x == 0) {
        int run = 0;
        for (int b = 0; b < nchunks; b++) {
            int v = chunkSum[b];
            chunkSum[b] = run;
            run += v;
        }
        rowPtr[N] = run;
    }
}

__global__ __launch_bounds__(512) void expand_scan_k(const int* __restrict__ deg,
                                                     const int* __restrict__ chunkOff,
                                                     int* __restrict__ rowPtr,
                                                     int* __restrict__ cursor, int N) {
    __shared__ int s[512];
    const int t = threadIdx.x;
    const int i = blockIdx.x * 512 + t;
    const int v = (i < N) ? deg[i] : 0;
    s[t] = v;
    __syncthreads();
    for (int off = 1; off < 512; off <<= 1) {
        int u = (t >= off) ? s[t - off] : 0;
        __syncthreads();
        s[t] += u;
        __syncthreads();
    }
    if (i < N) {
        int excl = s[t] - v + chunkOff[blockIdx.x];
        rowPtr[i] = excl;
        cursor[i] = excl;
    }
}

__global__ void fill_k(const int* __restrict__ src, const int* __restrict__ dst,
                       int* __restrict__ cursor, int* __restrict__ sortedSrc, int E) {
    int e = blockIdx.x * blockDim.x + threadIdx.x;
    if (e < E) {
        int pos = atomicAdd(&cursor[dst[e]], 1);
        sortedSrc[pos] = src[e];
    }
}

// ---------------- weight transpose + fp32->bf16 (unchanged, validated) ----------------
__global__ __launch_bounds__(256) void transpose_w_k(const float* __restrict__ convW,
                                                     const float* __restrict__ linW,
                                                     const float* __restrict__ clsW,
                                                     short* __restrict__ Wt) {
    const int b = blockIdx.x;
    const float* src;
    int NC;
    if (b < 9)       { src = convW + (size_t)b * 16384;      NC = 128; }
    else if (b < 12) { src = linW + (size_t)(b - 9) * 16384; NC = 128; }
    else             { src = clsW;                            NC = 64; }
    short* dst = Wt + (size_t)b * 16384;
    const int tot = NC * 32;
    for (int i = threadIdx.x; i < tot; i += 256) {
        int n = i >> 5, k0 = (i & 31) << 2;
        short4 s;
        s.x = f2bf(src[(k0 + 0) * NC + n]);
        s.y = f2bf(src[(k0 + 1) * NC + n]);
        s.z = f2bf(src[(k0 + 2) * NC + n]);
        s.w = f2bf(src[(k0 + 3) * NC + n]);
        *(short4*)&dst[n * 128 + k0] = s;
    }
}

// ---------------- x fp32 -> bf16 ----------------
__global__ void cast16_k(const float* __restrict__ x, short* __restrict__ x16, int n4) {
    int i = blockIdx.x * blockDim.x + threadIdx.x;
    int stride = gridDim.x * blockDim.x;
    for (; i < n4; i += stride) {
        float4 v = ((const float4*)x)[i];
        short4 s = {f2bf(v.x), f2bf(v.y), f2bf(v.z), f2bf(v.w)};
        ((short4*)x16)[i] = s;
    }
}

__global__ void zero_f_k(float* __restrict__ p, int n) {
    int i = blockIdx.x * blockDim.x + threadIdx.x;
    if (i < n) p[i] = 0.f;
}

// ---------------- aggregation, bf16 in/out: B16[i] = h16[i] + sum_j h16[src[j]] ----------------
// 32 lanes per node, 4 bf16 (8B) per lane; 8 nodes per 256-thread block.
__global__ __launch_bounds__(256) void agg16_k(const short* __restrict__ h16,
                                               const int* __restrict__ sortedSrc,
                                               const int* __restrict__ rowPtr,
                                               short* __restrict__ B16, int N) {
    const int node = blockIdx.x * 8 + (threadIdx.x >> 5);
    if (node >= N) return;
    const int f4 = (threadIdx.x & 31) << 2;
    short4 sv = *(const short4*)&h16[(size_t)node * 128 + f4];
    float a0 = bf2f(sv.x), a1 = bf2f(sv.y), a2 = bf2f(sv.z), a3 = bf2f(sv.w);
    const int beg = rowPtr[node], end = rowPtr[node + 1];
    for (int j = beg; j < end; j++) {
        int s = sortedSrc[j];
        short4 v = *(const short4*)&h16[(size_t)s * 128 + f4];
        a0 += bf2f(v.x); a1 += bf2f(v.y); a2 += bf2f(v.z); a3 += bf2f(v.w);
    }
    short4 o = {f2bf(a0), f2bf(a1), f2bf(a2), f2bf(a3)};
    *(short4*)&B16[(size_t)node * 128 + f4] = o;
}

// ---------------- bf16 MFMA GEMM, NCOLS=128: out = A16@W + bias (relu) ----------------
// OUT16: write bf16; else fp32. STATS: fused col sum/sumsq -> stats (global atomics).
// Fragment layout (validated R10): A lane=row(l&15),k=(l>>4)*8+e; D row=(l>>4)*4+j,col=l&15.
template <bool RELU, bool STATS, bool OUT16>
__global__ __launch_bounds__(256) void gemm16_k(const short* __restrict__ A16,
                                                const short* __restrict__ Wt,
                                                const float* __restrict__ bias,
                                                void* __restrict__ outv,
                                                float* __restrict__ stats, int N) {
    constexpr int LR = 136;
    __shared__ __align__(16) short sA[64 * LR];
    __shared__ __align__(16) short sW[128 * LR];
    __shared__ float sStats[256];
    const int t = threadIdx.x;
    const int row0 = blockIdx.x * 64;

    if (STATS) sStats[t] = 0.f;
    for (int i = t; i < 128 * 16; i += 256) {
        int n = i >> 4, k0 = (i & 15) << 3;
        *(bf16x8*)&sW[n * LR + k0] = *(const bf16x8*)&Wt[n * 128 + k0];
    }
    for (int i = t; i < 64 * 16; i += 256) {
        int r = i >> 4, k0 = (i & 15) << 3;
        int gr = row0 + r;
        bf16x8 v = {0, 0, 0, 0, 0, 0, 0, 0};
        if (gr < N) v = *(const bf16x8*)&A16[(size_t)gr * 128 + k0];
        *(bf16x8*)&sA[r * LR + k0] = v;
    }
    __syncthreads();

    const int w = t >> 6, l = t & 63;
    const int lr = l & 15, lg = l >> 4;

    bf16x8 af[4];
#pragma unroll
    for (int kb = 0; kb < 4; kb++)
        af[kb] = *(const bf16x8*)&sA[(w * 16 + lr) * LR + kb * 32 + lg * 8];

    f32x4 acc[8];
#pragma unroll
    for (int n = 0; n < 8; n++) acc[n] = {0.f, 0.f, 0.f, 0.f};

#pragma unroll
    for (int n = 0; n < 8; n++)
#pragma unroll
        for (int kb = 0; kb < 4; kb++) {
            bf16x8 bf = *(const bf16x8*)&sW[(n * 16 + lr) * LR + kb * 32 + lg * 8];
            acc[n] = __builtin_amdgcn_mfma_f32_16x16x32_bf16(af[kb], bf, acc[n], 0, 0, 0);
        }

#pragma unroll
    for (int n = 0; n < 8; n++) {
        const int col = n * 16 + lr;
        const float bv = bias[col];
        float part = 0.f, part2 = 0.f;
#pragma unroll
        for (int j = 0; j < 4; j++) {
            int r = row0 + w * 16 + lg * 4 + j;
            if (r < N) {
                float v = acc[n][j] + bv;
                if (RELU) v = fmaxf(v, 0.f);
                if (OUT16) ((short*)outv)[(size_t)r * 128 + col] = f2bf(v);
                else       ((float*)outv)[(size_t)r * 128 + col] = v;
                if (STATS) { part += v; part2 += v * v; }
            }
        }
        if (STATS) {
            atomicAdd(&sStats[col], part);
            atomicAdd(&sStats[128 + col], part2);
        }
    }
    if (STATS) {
        __syncthreads();
        atomicAdd(&stats[t], sStats[t]);
    }
}

// ---------------- BN apply: Z fp32 -> bf16 out ----------------
__global__ void bn_apply16_k(const float* __restrict__ Z, const float* __restrict__ stats,
                             const float* __restrict__ gamma, const float* __restrict__ beta,
                             short* __restrict__ out16, int N, int relu) {
    int i = blockIdx.x * blockDim.x + threadIdx.x;
    const int total = N * 32;
    const int stride = gridDim.x * blockDim.x;
    const float inv = 1.f / (float)N;
    for (; i < total; i += stride) {
        int c0 = (i & 31) * 4;
        float4 z = ((const float4*)Z)[i];
        float o[4] = {z.x, z.y, z.z, z.w};
        short r[4];
#pragma unroll
        for (int j = 0; j < 4; j++) {
            int c = c0 + j;
            float mean = stats[c] * inv;
            float var = stats[128 + c] * inv - mean * mean;
            float rstd = rsqrtf(var + 1e-5f);
            float v = (o[j] - mean) * rstd * gamma[c] + beta[c];
            if (relu) v = fmaxf(v, 0.f);
            r[j] = f2bf(v);
        }
        short4 ov = {r[0], r[1], r[2], r[3]};
        ((short4*)out16)[i] = ov;
    }
}

// ---------------- fused final: h = [H1|H2|H3]@linW+linB -> hout; logits = h@clsW+clsB ----------------
__global__ __launch_bounds__(256) void fuse3_k(const short* __restrict__ H0,
                                               const short* __restrict__ H1,
                                               const short* __restrict__ H2,
                                               const short* __restrict__ Wt,
                                               const float* __restrict__ linB,
                                               const float* __restrict__ clsB,
                                               float* __restrict__ hout,
                                               float* __restrict__ logits, int N) {
    constexpr int LR = 136;
    __shared__ __align__(16) short sA[64 * LR];
    __shared__ __align__(16) short sW[128 * LR];
    __shared__ __align__(16) short sH[64 * LR];
    const int t = threadIdx.x;
    const int row0 = blockIdx.x * 64;
    const int w = t >> 6, l = t & 63;
    const int lr = l & 15, lg = l >> 4;

    const short* Hs[3] = {H0, H1, H2};

    f32x4 acc[8];
#pragma unroll
    for (int n = 0; n < 8; n++) acc[n] = {0.f, 0.f, 0.f, 0.f};

    for (int s = 0; s < 3; s++) {
        const short* Hsrc = Hs[s];
        const short* Wsrc = Wt + (size_t)(9 + s) * 16384;
        for (int i = t; i < 128 * 16; i += 256) {
            int n = i >> 4, k0 = (i & 15) << 3;
            *(bf16x8*)&sW[n * LR + k0] = *(const bf16x8*)&Wsrc[n * 128 + k0];
        }
        for (int i = t; i < 64 * 16; i += 256) {
            int r = i >> 4, k0 = (i & 15) << 3;
            int gr = row0 + r;
            bf16x8 v = {0, 0, 0, 0, 0, 0, 0, 0};
            if (gr < N) v = *(const bf16x8*)&Hsrc[(size_t)gr * 128 + k0];
            *(bf16x8*)&sA[r * LR + k0] = v;
        }
        __syncthreads();
        bf16x8 af[4];
#pragma unroll
        for (int kb = 0; kb < 4; kb++)
            af[kb] = *(const bf16x8*)&sA[(w * 16 + lr) * LR + kb * 32 + lg * 8];
#pragma unroll
        for (int n = 0; n < 8; n++)
#pragma unroll
            for (int kb = 0; kb < 4; kb++) {
                bf16x8 bf = *(const bf16x8*)&sW[(n * 16 + lr) * LR + kb * 32 + lg * 8];
                acc[n] = __builtin_amdgcn_mfma_f32_16x16x32_bf16(af[kb], bf, acc[n], 0, 0, 0);
            }
        __syncthreads();
    }

    // h epilogue: hout fp32 + sH bf16 (D layout -> row-major LDS)
#pragma unroll
    for (int n = 0; n < 8; n++) {
        const int col = n * 16 + lr;
        const float bv = linB[col];
#pragma unroll
        for (int j = 0; j < 4; j++) {
            int rloc = w * 16 + lg * 4 + j;
            int r = row0 + rloc;
            float v = acc[n][j] + bv;
            if (r < N) hout[(size_t)r * 128 + col] = v;
            sH[rloc * LR + col] = f2bf(v);
        }
    }
    // stage cls weights (64 rows) into sW
    for (int i = t; i < 64 * 16; i += 256) {
        int n = i >> 4, k0 = (i & 15) << 3;
        *(bf16x8*)&sW[n * LR + k0] = *(const bf16x8*)&Wt[(size_t)12 * 16384 + n * 128 + k0];
    }
    __syncthreads();

    bf16x8 ah[4];
#pragma unroll
    for (int kb = 0; kb < 4; kb++)
        ah[kb] = *(const bf16x8*)&sH[(w * 16 + lr) * LR + kb * 32 + lg * 8];

    f32x4 acc2[4];
#pragma unroll
    for (int n = 0; n < 4; n++) acc2[n] = {0.f, 0.f, 0.f, 0.f};
#pragma unroll
    for (int n = 0; n < 4; n++)
#pragma unroll
        for (int kb = 0; kb < 4; kb++) {
            bf16x8 bf = *(const bf16x8*)&sW[(n * 16 + lr) * LR + kb * 32 + lg * 8];
            acc2[n] = __builtin_amdgcn_mfma_f32_16x16x32_bf16(ah[kb], bf, acc2[n], 0, 0, 0);
        }
#pragma unroll
    for (int n = 0; n < 4; n++) {
        const int col = n * 16 + lr;
        const float bv = clsB[col];
#pragma unroll
        for (int j = 0; j < 4; j++) {
            int r = row0 + w * 16 + lg * 4 + j;
            if (r < N) logits[(size_t)r * 64 + col] = acc2[n][j] + bv;
        }
    }
}

// ---------------- launch ----------------

extern "C" void kernel_launch(void* const* d_in, const int* in_sizes, int n_in,
                              void* d_out, int out_size, void* d_ws, size_t ws_size,
                              hipStream_t stream) {
    const float* x     = (const float*)d_in[0];
    const int*   ei    = (const int*)d_in[1];
    const float* convW = (const float*)d_in[2];
    const float* convB = (const float*)d_in[3];
    const float* gamma = (const float*)d_in[4];
    const float* beta  = (const float*)d_in[5];
    const float* linW  = (const float*)d_in[6];
    const float* linB  = (const float*)d_in[7];
    const float* clsW  = (const float*)d_in[8];
    const float* clsB  = (const float*)d_in[9];

    const int N = in_sizes[0] / 128;   // 50000
    const int E = in_sizes[1] / 2;     // 800000
    const int* src = ei;
    const int* dst = ei + E;

    float* Z    = (float*)d_ws;                    // N*128 fp32; first half doubles as B16
    short* B16  = (short*)Z;                       // alias (disjoint lifetime)
    short* C16  = (short*)(Z + (size_t)N * 128);   // also x16 before layer 0
    short* H16  = C16 + (size_t)N * 128;           // 3 buffers of N*128
    float* stats = (float*)(H16 + (size_t)3 * N * 128);   // 768 floats
    int* deg       = (int*)(stats + 768);
    int* rowPtr    = deg + N;
    int* cursor    = rowPtr + (N + 1);
    int* chunkSum  = cursor + N;
    int* sortedSrc = chunkSum + 512;
    short* Wt = (short*)((((uintptr_t)(sortedSrc + E)) + 15) & ~(uintptr_t)15);

    float* logits = (float*)d_out;
    float* hout   = (float*)d_out + (size_t)N * 64;

    const int nchunks = (N + 511) / 512;
    const int eb = (E + 255) / 256;

    // ---- CSR build ----
    zero_int_k<<<(N + 255) / 256, 256, 0, stream>>>(deg, N);
    deg_count_k<<<eb, 256, 0, stream>>>(dst, deg, E);
    chunk_reduce_k<<<nchunks, 512, 0, stream>>>(deg, chunkSum, N);
    scan_chunks_k<<<1, 64, 0, stream>>>(chunkSum, rowPtr, nchunks, N);
    expand_scan_k<<<nchunks, 512, 0, stream>>>(deg, chunkSum, rowPtr, cursor, N);
    fill_k<<<eb, 256, 0, stream>>>(src, dst, cursor, sortedSrc, E);

    // ---- weights -> bf16 transposed; x -> bf16; stats -> 0 ----
    transpose_w_k<<<13, 256, 0, stream>>>(convW, linW, clsW, Wt);
    cast16_k<<<1024, 256, 0, stream>>>(x, C16, N * 32);
    zero_f_k<<<3, 256, 0, stream>>>(stats, 768);

    const int nbm = (N + 63) / 64;
    const int aggb = (N + 7) / 8;

    const short* hin16 = C16;
    for (int li = 0; li < 3; li++) {
        agg16_k<<<aggb, 256, 0, stream>>>(hin16, sortedSrc, rowPtr, B16, N);

        const short* Wt0 = Wt + (size_t)(li * 3 + 0) * 16384;
        const short* Wt1 = Wt + (size_t)(li * 3 + 1) * 16384;
        const short* Wt2 = Wt + (size_t)(li * 3 + 2) * 16384;
        const float* b0 = convB + ((size_t)li * 3 + 0) * 128;
        const float* b1 = convB + ((size_t)li * 3 + 1) * 128;
        const float* b2 = convB + ((size_t)li * 3 + 2) * 128;
        float* statL = stats + (size_t)li * 256;

        gemm16_k<true,  false, true ><<<nbm, 256, 0, stream>>>(B16, Wt0, b0, C16, nullptr, N);
        gemm16_k<true,  false, true ><<<nbm, 256, 0, stream>>>(C16, Wt1, b1, C16, nullptr, N);
        gemm16_k<false, true,  false><<<nbm, 256, 0, stream>>>(C16, Wt2, b2, Z, statL, N);

        short* HL = H16 + (size_t)li * N * 128;
        bn_apply16_k<<<2048, 256, 0, stream>>>(Z, statL, gamma + li * 128, beta + li * 128,
                                               HL, N, li < 2 ? 1 : 0);
        hin16 = HL;
    }

    fuse3_k<<<nbm, 256, 0, stream>>>(H16, H16 + (size_t)N * 128, H16 + (size_t)2 * N * 128,
                                     Wt, linB, clsB, hout, logits, N);
}

// Round 12
// 490.379 us; speedup vs baseline: 2.9935x; 1.3269x over previous
//
#include <hip/hip_runtime.h>
#include <hip/hip_bf16.h>
#include <stdint.h>

// GIN 3-layer forward on MI355X. Round 12:
//  - agg16_k: 4x-unrolled gather (ILP on the latency chain) + optional fused BN affine+relu
//  - mlp_layer_k: per-layer 3-GEMM MLP in ONE kernel (in-place LDS chaining, wave-exclusive rows)
//  - BN folded to affine (s,t) via bnparam_k; bn_apply eliminated; Z stored bf16
//  - fuse3_k stages H = affine(Z) (+relu l<2) on load; h=concat@linW+linB; logits=h@clsW+clsB

using bf16x8 = __attribute__((ext_vector_type(8))) short;
using f32x4  = __attribute__((ext_vector_type(4))) float;

__device__ inline short f2bf(float f) {
    union { __hip_bfloat16 h; short s; } u;
    u.h = __float2bfloat16(f);
    return u.s;
}
__device__ inline float bf2f(short s) {
    union { uint32_t u; float f; } c;
    c.u = ((uint32_t)(uint16_t)s) << 16;
    return c.f;
}

// ---------------- CSR build (unchanged, validated) ----------------

__global__ void zero_int_k(int* __restrict__ p, int n) {
    int i = blockIdx.x * blockDim.x + threadIdx.x;
    if (i < n) p[i] = 0;
}

__global__ void deg_count_k(const int* __restrict__ dst, int* __restrict__ deg, int E) {
    int e = blockIdx.x * blockDim.x + threadIdx.x;
    if (e < E) atomicAdd(&deg[dst[e]], 1);
}

__global__ __launch_bounds__(512) void chunk_reduce_k(const int* __restrict__ deg,
                                                      int* __restrict__ chunkSum, int N) {
    __shared__ int s[512];
    int i = blockIdx.x * 512 + threadIdx.x;
    s[threadIdx.x] = (i < N) ? deg[i] : 0;
    __syncthreads();
    for (int off = 256; off > 0; off >>= 1) {
        if (threadIdx.x < off) s[threadIdx.x] += s[threadIdx.x + off];
        __syncthreads();
    }
    if (threadIdx.x == 0) chunkSum[blockIdx.x] = s[0];
}

__global__ void scan_chunks_k(int* __restrict__ chunkSum, int* __restrict__ rowPtr,
                              int nchunks, int N) {
    if (threadIdx.x == 0 && blockIdx.x == 0) {
        int run = 0;
        for (int b = 0; b < nchunks; b++) {
            int v = chunkSum[b];
            chunkSum[b] = run;
            run += v;
        }
        rowPtr[N] = run;
    }
}

__global__ __launch_bounds__(512) void expand_scan_k(const int* __restrict__ deg,
                                                     const int* __restrict__ chunkOff,
                                                     int* __restrict__ rowPtr,
                                                     int* __restrict__ cursor, int N) {
    __shared__ int s[512];
    const int t = threadIdx.x;
    const int i = blockIdx.x * 512 + t;
    const int v = (i < N) ? deg[i] : 0;
    s[t] = v;
    __syncthreads();
    for (int off = 1; off < 512; off <<= 1) {
        int u = (t >= off) ? s[t - off] : 0;
        __syncthreads();
        s[t] += u;
        __syncthreads();
    }
    if (i < N) {
        int excl = s[t] - v + chunkOff[blockIdx.x];
        rowPtr[i] = excl;
        cursor[i] = excl;
    }
}

__global__ void fill_k(const int* __restrict__ src, const int* __restrict__ dst,
                       int* __restrict__ cursor, int* __restrict__ sortedSrc, int E) {
    int e = blockIdx.x * blockDim.x + threadIdx.x;
    if (e < E) {
        int pos = atomicAdd(&cursor[dst[e]], 1);
        sortedSrc[pos] = src[e];
    }
}

// ---------------- weight transpose + fp32->bf16 (unchanged, validated) ----------------
__global__ __launch_bounds__(256) void transpose_w_k(const float* __restrict__ convW,
                                                     const float* __restrict__ linW,
                                                     const float* __restrict__ clsW,
                                                     short* __restrict__ Wt) {
    const int b = blockIdx.x;
    const float* src;
    int NC;
    if (b < 9)       { src = convW + (size_t)b * 16384;      NC = 128; }
    else if (b < 12) { src = linW + (size_t)(b - 9) * 16384; NC = 128; }
    else             { src = clsW;                            NC = 64; }
    short* dst = Wt + (size_t)b * 16384;
    const int tot = NC * 32;
    for (int i = threadIdx.x; i < tot; i += 256) {
        int n = i >> 5, k0 = (i & 31) << 2;
        short4 s;
        s.x = f2bf(src[(k0 + 0) * NC + n]);
        s.y = f2bf(src[(k0 + 1) * NC + n]);
        s.z = f2bf(src[(k0 + 2) * NC + n]);
        s.w = f2bf(src[(k0 + 3) * NC + n]);
        *(short4*)&dst[n * 128 + k0] = s;
    }
}

__global__ void cast16_k(const float* __restrict__ x, short* __restrict__ x16, int n4) {
    int i = blockIdx.x * blockDim.x + threadIdx.x;
    int stride = gridDim.x * blockDim.x;
    for (; i < n4; i += stride) {
        float4 v = ((const float4*)x)[i];
        short4 s = {f2bf(v.x), f2bf(v.y), f2bf(v.z), f2bf(v.w)};
        ((short4*)x16)[i] = s;
    }
}

__global__ void zero_f_k(float* __restrict__ p, int n) {
    int i = blockIdx.x * blockDim.x + threadIdx.x;
    if (i < n) p[i] = 0.f;
}

// ---------------- BN -> affine params: s = gamma*rsqrt(var+eps), t = beta - mean*s ----------------
__global__ void bnparam_k(const float* __restrict__ stats, const float* __restrict__ gamma,
                          const float* __restrict__ beta, float* __restrict__ sb, int N) {
    int c = threadIdx.x;   // 128
    float inv = 1.f / (float)N;
    float mean = stats[c] * inv;
    float var = stats[128 + c] * inv - mean * mean;
    float s = gamma[c] * rsqrtf(var + 1e-5f);
    sb[c] = s;
    sb[128 + c] = beta[c] - mean * s;
}

// ---------------- aggregation: B16[i] = g(h[i]) + sum_j g(h[src[j]]), g = relu(affine) or id ----------------
// 32 lanes/node, 4 bf16 per lane; 4x unrolled gather for ILP.
template <bool AFFINE>
__global__ __launch_bounds__(256) void agg16_k(const short* __restrict__ h16,
                                               const int* __restrict__ sortedSrc,
                                               const int* __restrict__ rowPtr,
                                               const float* __restrict__ sb,
                                               short* __restrict__ B16, int N) {
    const int node = blockIdx.x * 8 + (threadIdx.x >> 5);
    if (node >= N) return;
    const int f4 = (threadIdx.x & 31) << 2;
    float s0 = 1.f, s1 = 1.f, s2 = 1.f, s3 = 1.f, t0 = 0.f, t1 = 0.f, t2 = 0.f, t3 = 0.f;
    if (AFFINE) {
        float4 sv = *(const float4*)&sb[f4];
        float4 tv = *(const float4*)&sb[128 + f4];
        s0 = sv.x; s1 = sv.y; s2 = sv.z; s3 = sv.w;
        t0 = tv.x; t1 = tv.y; t2 = tv.z; t3 = tv.w;
    }
    float a0 = 0.f, a1 = 0.f, a2 = 0.f, a3 = 0.f;

#define GACC(v) { \
    float x0 = bf2f((v).x), x1 = bf2f((v).y), x2 = bf2f((v).z), x3 = bf2f((v).w); \
    if (AFFINE) { \
        x0 = fmaxf(fmaf(x0, s0, t0), 0.f); x1 = fmaxf(fmaf(x1, s1, t1), 0.f); \
        x2 = fmaxf(fmaf(x2, s2, t2), 0.f); x3 = fmaxf(fmaf(x3, s3, t3), 0.f); } \
    a0 += x0; a1 += x1; a2 += x2; a3 += x3; }

    short4 self = *(const short4*)&h16[(size_t)node * 128 + f4];
    GACC(self);

    const int beg = rowPtr[node], end = rowPtr[node + 1];
    int j = beg;
    for (; j + 4 <= end; j += 4) {
        int i0 = sortedSrc[j], i1 = sortedSrc[j + 1], i2 = sortedSrc[j + 2], i3 = sortedSrc[j + 3];
        short4 v0 = *(const short4*)&h16[(size_t)i0 * 128 + f4];
        short4 v1 = *(const short4*)&h16[(size_t)i1 * 128 + f4];
        short4 v2 = *(const short4*)&h16[(size_t)i2 * 128 + f4];
        short4 v3 = *(const short4*)&h16[(size_t)i3 * 128 + f4];
        GACC(v0); GACC(v1); GACC(v2); GACC(v3);
    }
    for (; j < end; j++) {
        int ii = sortedSrc[j];
        short4 v = *(const short4*)&h16[(size_t)ii * 128 + f4];
        GACC(v);
    }
#undef GACC

    short4 o = {f2bf(a0), f2bf(a1), f2bf(a2), f2bf(a3)};
    *(short4*)&B16[(size_t)node * 128 + f4] = o;
}

// ---------------- fused per-layer MLP: Z16 = (relu(relu(B@W0+b0)@W1+b1))@W2+b2, stats fused ----------------
// 256 threads, BM=64. In-place LDS chaining: wave w's D-rows == wave w's A-rows (validated
// fragment mapping), so each phase writes bf16 results back into sA rows it exclusively owns.
// Per-wave LDS ordering (reads issued before dependent writes) makes this safe; sW is
// re-staged per phase behind barriers.
__global__ __launch_bounds__(256) void mlp_layer_k(const short* __restrict__ B16,
                                                   const short* __restrict__ Wt0,
                                                   const short* __restrict__ Wt1,
                                                   const short* __restrict__ Wt2,
                                                   const float* __restrict__ b0,
                                                   const float* __restrict__ b1,
                                                   const float* __restrict__ b2,
                                                   short* __restrict__ Z16,
                                                   float* __restrict__ stats, int N) {
    constexpr int LR = 136;
    __shared__ __align__(16) short sA[64 * LR];
    __shared__ __align__(16) short sW[128 * LR];
    __shared__ float sStats[256];
    const int t = threadIdx.x;
    const int row0 = blockIdx.x * 64;
    const int w = t >> 6, l = t & 63;
    const int lr = l & 15, lg = l >> 4;

    sStats[t] = 0.f;
    for (int i = t; i < 64 * 16; i += 256) {
        int r = i >> 4, k0 = (i & 15) << 3;
        int gr = row0 + r;
        bf16x8 v = {0, 0, 0, 0, 0, 0, 0, 0};
        if (gr < N) v = *(const bf16x8*)&B16[(size_t)gr * 128 + k0];
        *(bf16x8*)&sA[r * LR + k0] = v;
    }

    const short* Ws[3] = {Wt0, Wt1, Wt2};
    const float* bs[3] = {b0, b1, b2};

    for (int ph = 0; ph < 3; ph++) {
        __syncthreads();                       // prior phase done reading sW (and sA staged)
        for (int i = t; i < 128 * 16; i += 256) {
            int n = i >> 4, k0 = (i & 15) << 3;
            *(bf16x8*)&sW[n * LR + k0] = *(const bf16x8*)&Ws[ph][n * 128 + k0];
        }
        __syncthreads();

        bf16x8 af[4];
#pragma unroll
        for (int kb = 0; kb < 4; kb++)
            af[kb] = *(const bf16x8*)&sA[(w * 16 + lr) * LR + kb * 32 + lg * 8];

        f32x4 acc[8];
#pragma unroll
        for (int n = 0; n < 8; n++) acc[n] = {0.f, 0.f, 0.f, 0.f};
#pragma unroll
        for (int n = 0; n < 8; n++)
#pragma unroll
            for (int kb = 0; kb < 4; kb++) {
                bf16x8 bf = *(const bf16x8*)&sW[(n * 16 + lr) * LR + kb * 32 + lg * 8];
                acc[n] = __builtin_amdgcn_mfma_f32_16x16x32_bf16(af[kb], bf, acc[n], 0, 0, 0);
            }

        const float* bias = bs[ph];
        if (ph < 2) {
#pragma unroll
            for (int n = 0; n < 8; n++) {
                const int col = n * 16 + lr;
                const float bv = bias[col];
#pragma unroll
                for (int j = 0; j < 4; j++) {
                    int rloc = w * 16 + lg * 4 + j;
                    float v = fmaxf(acc[n][j] + bv, 0.f);
                    sA[rloc * LR + col] = f2bf(v);
                }
            }
        } else {
#pragma unroll
            for (int n = 0; n < 8; n++) {
                const int col = n * 16 + lr;
                const float bv = bias[col];
                float part = 0.f, part2 = 0.f;
#pragma unroll
                for (int j = 0; j < 4; j++) {
                    int r = row0 + w * 16 + lg * 4 + j;
                    if (r < N) {
                        float v = acc[n][j] + bv;
                        Z16[(size_t)r * 128 + col] = f2bf(v);
                        part += v; part2 += v * v;
                    }
                }
                atomicAdd(&sStats[col], part);
                atomicAdd(&sStats[128 + col], part2);
            }
        }
    }
    __syncthreads();
    atomicAdd(&stats[t], sStats[t]);
}

// ---------------- fused final: h = [g0(Z0)|g1(Z1)|g2(Z2)]@linW+linB -> hout; logits = h@clsW+clsB ----------------
__global__ __launch_bounds__(256) void fuse3_k(const short* __restrict__ Z0,
                                               const short* __restrict__ Z1,
                                               const short* __restrict__ Z2,
                                               const float* __restrict__ sb,
                                               const short* __restrict__ Wt,
                                               const float* __restrict__ linB,
                                               const float* __restrict__ clsB,
                                               float* __restrict__ hout,
                                               float* __restrict__ logits, int N) {
    constexpr int LR = 136;
    __shared__ __align__(16) short sA[64 * LR];
    __shared__ __align__(16) short sW[128 * LR];
    __shared__ __align__(16) short sH[64 * LR];
    const int t = threadIdx.x;
    const int row0 = blockIdx.x * 64;
    const int w = t >> 6, l = t & 63;
    const int lr = l & 15, lg = l >> 4;

    const short* Zs[3] = {Z0, Z1, Z2};

    f32x4 acc[8];
#pragma unroll
    for (int n = 0; n < 8; n++) acc[n] = {0.f, 0.f, 0.f, 0.f};

    for (int s = 0; s < 3; s++) {
        const short* Zsrc = Zs[s];
        const short* Wsrc = Wt + (size_t)(9 + s) * 16384;
        const float* ss = sb + (size_t)s * 256;
        const float* tt = ss + 128;
        for (int i = t; i < 128 * 16; i += 256) {
            int n = i >> 4, k0 = (i & 15) << 3;
            *(bf16x8*)&sW[n * LR + k0] = *(const bf16x8*)&Wsrc[n * 128 + k0];
        }
        for (int i = t; i < 64 * 16; i += 256) {
            int r = i >> 4, k0 = (i & 15) << 3;
            int gr = row0 + r;
            bf16x8 v = {0, 0, 0, 0, 0, 0, 0, 0};
            if (gr < N) {
                bf16x8 z = *(const bf16x8*)&Zsrc[(size_t)gr * 128 + k0];
#pragma unroll
                for (int e = 0; e < 8; e++) {
                    float xv = fmaf(bf2f(z[e]), ss[k0 + e], tt[k0 + e]);
                    if (s < 2) xv = fmaxf(xv, 0.f);
                    v[e] = f2bf(xv);
                }
            }
            *(bf16x8*)&sA[r * LR + k0] = v;
        }
        __syncthreads();
        bf16x8 af[4];
#pragma unroll
        for (int kb = 0; kb < 4; kb++)
            af[kb] = *(const bf16x8*)&sA[(w * 16 + lr) * LR + kb * 32 + lg * 8];
#pragma unroll
        for (int n = 0; n < 8; n++)
#pragma unroll
            for (int kb = 0; kb < 4; kb++) {
                bf16x8 bf = *(const bf16x8*)&sW[(n * 16 + lr) * LR + kb * 32 + lg * 8];
                acc[n] = __builtin_amdgcn_mfma_f32_16x16x32_bf16(af[kb], bf, acc[n], 0, 0, 0);
            }
        __syncthreads();
    }

#pragma unroll
    for (int n = 0; n < 8; n++) {
        const int col = n * 16 + lr;
        const float bv = linB[col];
#pragma unroll
        for (int j = 0; j < 4; j++) {
            int rloc = w * 16 + lg * 4 + j;
            int r = row0 + rloc;
            float v = acc[n][j] + bv;
            if (r < N) hout[(size_t)r * 128 + col] = v;
            sH[rloc * LR + col] = f2bf(v);
        }
    }
    for (int i = t; i < 64 * 16; i += 256) {
        int n = i >> 4, k0 = (i & 15) << 3;
        *(bf16x8*)&sW[n * LR + k0] = *(const bf16x8*)&Wt[(size_t)12 * 16384 + n * 128 + k0];
    }
    __syncthreads();

    bf16x8 ah[4];
#pragma unroll
    for (int kb = 0; kb < 4; kb++)
        ah[kb] = *(const bf16x8*)&sH[(w * 16 + lr) * LR + kb * 32 + lg * 8];

    f32x4 acc2[4];
#pragma unroll
    for (int n = 0; n < 4; n++) acc2[n] = {0.f, 0.f, 0.f, 0.f};
#pragma unroll
    for (int n = 0; n < 4; n++)
#pragma unroll
        for (int kb = 0; kb < 4; kb++) {
            bf16x8 bf = *(const bf16x8*)&sW[(n * 16 + lr) * LR + kb * 32 + lg * 8];
            acc2[n] = __builtin_amdgcn_mfma_f32_16x16x32_bf16(ah[kb], bf, acc2[n], 0, 0, 0);
        }
#pragma unroll
    for (int n = 0; n < 4; n++) {
        const int col = n * 16 + lr;
        const float bv = clsB[col];
#pragma unroll
        for (int j = 0; j < 4; j++) {
            int r = row0 + w * 16 + lg * 4 + j;
            if (r < N) logits[(size_t)r * 64 + col] = acc2[n][j] + bv;
        }
    }
}

// ---------------- launch ----------------

extern "C" void kernel_launch(void* const* d_in, const int* in_sizes, int n_in,
                              void* d_out, int out_size, void* d_ws, size_t ws_size,
                              hipStream_t stream) {
    const float* x     = (const float*)d_in[0];
    const int*   ei    = (const int*)d_in[1];
    const float* convW = (const float*)d_in[2];
    const float* convB = (const float*)d_in[3];
    const float* gamma = (const float*)d_in[4];
    const float* beta  = (const float*)d_in[5];
    const float* linW  = (const float*)d_in[6];
    const float* linB  = (const float*)d_in[7];
    const float* clsW  = (const float*)d_in[8];
    const float* clsB  = (const float*)d_in[9];

    const int N = in_sizes[0] / 128;   // 50000
    const int E = in_sizes[1] / 2;     // 800000
    const int* src = ei;
    const int* dst = ei + E;

    short* x16 = (short*)d_ws;                       // N*128
    short* B16 = x16 + (size_t)N * 128;              // N*128
    short* Z16 = B16 + (size_t)N * 128;              // 3 x N*128
    float* stats = (float*)(Z16 + (size_t)3 * N * 128);  // 768
    float* sb    = stats + 768;                      // 768 (3 x [s128|t128])
    int* deg       = (int*)(sb + 768);
    int* rowPtr    = deg + N;
    int* cursor    = rowPtr + (N + 1);
    int* chunkSum  = cursor + N;
    int* sortedSrc = chunkSum + 512;
    short* Wt = (short*)((((uintptr_t)(sortedSrc + E)) + 15) & ~(uintptr_t)15);

    float* logits = (float*)d_out;
    float* hout   = (float*)d_out + (size_t)N * 64;

    const int nchunks = (N + 511) / 512;
    const int eb = (E + 255) / 256;

    // ---- CSR build ----
    zero_int_k<<<(N + 255) / 256, 256, 0, stream>>>(deg, N);
    deg_count_k<<<eb, 256, 0, stream>>>(dst, deg, E);
    chunk_reduce_k<<<nchunks, 512, 0, stream>>>(deg, chunkSum, N);
    scan_chunks_k<<<1, 64, 0, stream>>>(chunkSum, rowPtr, nchunks, N);
    expand_scan_k<<<nchunks, 512, 0, stream>>>(deg, chunkSum, rowPtr, cursor, N);
    fill_k<<<eb, 256, 0, stream>>>(src, dst, cursor, sortedSrc, E);

    transpose_w_k<<<13, 256, 0, stream>>>(convW, linW, clsW, Wt);
    cast16_k<<<1024, 256, 0, stream>>>(x, x16, N * 32);
    zero_f_k<<<3, 256, 0, stream>>>(stats, 768);

    const int nbm = (N + 63) / 64;
    const int aggb = (N + 7) / 8;

    for (int li = 0; li < 3; li++) {
        const short* hin16 = (li == 0) ? x16 : (Z16 + (size_t)(li - 1) * N * 128);
        const float* sbl   = sb + (size_t)(li - 1) * 256;   // unused when li==0
        if (li == 0)
            agg16_k<false><<<aggb, 256, 0, stream>>>(hin16, sortedSrc, rowPtr, nullptr, B16, N);
        else
            agg16_k<true><<<aggb, 256, 0, stream>>>(hin16, sortedSrc, rowPtr, sbl, B16, N);

        const short* Wt0 = Wt + (size_t)(li * 3 + 0) * 16384;
        const short* Wt1 = Wt + (size_t)(li * 3 + 1) * 16384;
        const short* Wt2 = Wt + (size_t)(li * 3 + 2) * 16384;
        const float* b0 = convB + ((size_t)li * 3 + 0) * 128;
        const float* b1 = convB + ((size_t)li * 3 + 1) * 128;
        const float* b2 = convB + ((size_t)li * 3 + 2) * 128;
        float* statL = stats + (size_t)li * 256;

        mlp_layer_k<<<nbm, 256, 0, stream>>>(B16, Wt0, Wt1, Wt2, b0, b1, b2,
                                             Z16 + (size_t)li * N * 128, statL, N);
        bnparam_k<<<1, 128, 0, stream>>>(statL, gamma + li * 128, beta + li * 128,
                                         sb + (size_t)li * 256, N);
    }

    fuse3_k<<<nbm, 256, 0, stream>>>(Z16, Z16 + (size_t)N * 128, Z16 + (size_t)2 * N * 128,
                                     sb, Wt, linB, clsB, hout, logits, N);
}

// Round 13
// 481.068 us; speedup vs baseline: 3.0515x; 1.0194x over previous
//
#include <hip/hip_runtime.h>
#include <hip/hip_bf16.h>
#include <stdint.h>

// GIN 3-layer forward on MI355X. Round 13:
//  - mlp_layer_k: NO global atomics (per-block partial stats, coalesced store);
//    next-phase W prefetched into registers during MFMA phase.
//  - stats_reduce_k: 49-block coalesced reduction partial -> stats.
//  - agg16_k: gather unrolled 8x (latency-bound chain, L2/L3-resident reads).
//  - everything else unchanged from validated R12.

using bf16x8 = __attribute__((ext_vector_type(8))) short;
using f32x4  = __attribute__((ext_vector_type(4))) float;

__device__ inline short f2bf(float f) {
    union { __hip_bfloat16 h; short s; } u;
    u.h = __float2bfloat16(f);
    return u.s;
}
__device__ inline float bf2f(short s) {
    union { uint32_t u; float f; } c;
    c.u = ((uint32_t)(uint16_t)s) << 16;
    return c.f;
}

// ---------------- CSR build (unchanged, validated) ----------------

__global__ void zero_int_k(int* __restrict__ p, int n) {
    int i = blockIdx.x * blockDim.x + threadIdx.x;
    if (i < n) p[i] = 0;
}

__global__ void deg_count_k(const int* __restrict__ dst, int* __restrict__ deg, int E) {
    int e = blockIdx.x * blockDim.x + threadIdx.x;
    if (e < E) atomicAdd(&deg[dst[e]], 1);
}

__global__ __launch_bounds__(512) void chunk_reduce_k(const int* __restrict__ deg,
                                                      int* __restrict__ chunkSum, int N) {
    __shared__ int s[512];
    int i = blockIdx.x * 512 + threadIdx.x;
    s[threadIdx.x] = (i < N) ? deg[i] : 0;
    __syncthreads();
    for (int off = 256; off > 0; off >>= 1) {
        if (threadIdx.x < off) s[threadIdx.x] += s[threadIdx.x + off];
        __syncthreads();
    }
    if (threadIdx.x == 0) chunkSum[blockIdx.x] = s[0];
}

__global__ void scan_chunks_k(int* __restrict__ chunkSum, int* __restrict__ rowPtr,
                              int nchunks, int N) {
    if (threadIdx.x == 0 && blockIdx.x == 0) {
        int run = 0;
        for (int b = 0; b < nchunks; b++) {
            int v = chunkSum[b];
            chunkSum[b] = run;
            run += v;
        }
        rowPtr[N] = run;
    }
}

__global__ __launch_bounds__(512) void expand_scan_k(const int* __restrict__ deg,
                                                     const int* __restrict__ chunkOff,
                                                     int* __restrict__ rowPtr,
                                                     int* __restrict__ cursor, int N) {
    __shared__ int s[512];
    const int t = threadIdx.x;
    const int i = blockIdx.x * 512 + t;
    const int v = (i < N) ? deg[i] : 0;
    s[t] = v;
    __syncthreads();
    for (int off = 1; off < 512; off <<= 1) {
        int u = (t >= off) ? s[t - off] : 0;
        __syncthreads();
        s[t] += u;
        __syncthreads();
    }
    if (i < N) {
        int excl = s[t] - v + chunkOff[blockIdx.x];
        rowPtr[i] = excl;
        cursor[i] = excl;
    }
}

__global__ void fill_k(const int* __restrict__ src, const int* __restrict__ dst,
                       int* __restrict__ cursor, int* __restrict__ sortedSrc, int E) {
    int e = blockIdx.x * blockDim.x + threadIdx.x;
    if (e < E) {
        int pos = atomicAdd(&cursor[dst[e]], 1);
        sortedSrc[pos] = src[e];
    }
}

// ---------------- weight transpose + fp32->bf16 (unchanged, validated) ----------------
__global__ __launch_bounds__(256) void transpose_w_k(const float* __restrict__ convW,
                                                     const float* __restrict__ linW,
                                                     const float* __restrict__ clsW,
                                                     short* __restrict__ Wt) {
    const int b = blockIdx.x;
    const float* src;
    int NC;
    if (b < 9)       { src = convW + (size_t)b * 16384;      NC = 128; }
    else if (b < 12) { src = linW + (size_t)(b - 9) * 16384; NC = 128; }
    else             { src = clsW;                            NC = 64; }
    short* dst = Wt + (size_t)b * 16384;
    const int tot = NC * 32;
    for (int i = threadIdx.x; i < tot; i += 256) {
        int n = i >> 5, k0 = (i & 31) << 2;
        short4 s;
        s.x = f2bf(src[(k0 + 0) * NC + n]);
        s.y = f2bf(src[(k0 + 1) * NC + n]);
        s.z = f2bf(src[(k0 + 2) * NC + n]);
        s.w = f2bf(src[(k0 + 3) * NC + n]);
        *(short4*)&dst[n * 128 + k0] = s;
    }
}

__global__ void cast16_k(const float* __restrict__ x, short* __restrict__ x16, int n4) {
    int i = blockIdx.x * blockDim.x + threadIdx.x;
    int stride = gridDim.x * blockDim.x;
    for (; i < n4; i += stride) {
        float4 v = ((const float4*)x)[i];
        short4 s = {f2bf(v.x), f2bf(v.y), f2bf(v.z), f2bf(v.w)};
        ((short4*)x16)[i] = s;
    }
}

__global__ void zero_f_k(float* __restrict__ p, int n) {
    int i = blockIdx.x * blockDim.x + threadIdx.x;
    if (i < n) p[i] = 0.f;
}

// ---------------- partial-stats reduction: stats[c] += sum_b partial[b][c] ----------------
__global__ __launch_bounds__(256) void stats_reduce_k(const float* __restrict__ partial,
                                                      float* __restrict__ stats, int nb) {
    const int c = threadIdx.x;
    const int b0 = blockIdx.x * 16;
    const int bend = min(nb, b0 + 16);
    float s = 0.f;
    for (int b = b0; b < bend; b++)
        s += partial[(size_t)b * 256 + c];
    atomicAdd(&stats[c], s);
}

// ---------------- BN -> affine params ----------------
__global__ void bnparam_k(const float* __restrict__ stats, const float* __restrict__ gamma,
                          const float* __restrict__ beta, float* __restrict__ sb, int N) {
    int c = threadIdx.x;   // 128
    float inv = 1.f / (float)N;
    float mean = stats[c] * inv;
    float var = stats[128 + c] * inv - mean * mean;
    float s = gamma[c] * rsqrtf(var + 1e-5f);
    sb[c] = s;
    sb[128 + c] = beta[c] - mean * s;
}

// ---------------- aggregation: B16[i] = g(h[i]) + sum_j g(h[src[j]]), 8x unroll ----------------
template <bool AFFINE>
__global__ __launch_bounds__(256) void agg16_k(const short* __restrict__ h16,
                                               const int* __restrict__ sortedSrc,
                                               const int* __restrict__ rowPtr,
                                               const float* __restrict__ sb,
                                               short* __restrict__ B16, int N) {
    const int node = blockIdx.x * 8 + (threadIdx.x >> 5);
    if (node >= N) return;
    const int f4 = (threadIdx.x & 31) << 2;
    float s0 = 1.f, s1 = 1.f, s2 = 1.f, s3 = 1.f, t0 = 0.f, t1 = 0.f, t2 = 0.f, t3 = 0.f;
    if (AFFINE) {
        float4 sv = *(const float4*)&sb[f4];
        float4 tv = *(const float4*)&sb[128 + f4];
        s0 = sv.x; s1 = sv.y; s2 = sv.z; s3 = sv.w;
        t0 = tv.x; t1 = tv.y; t2 = tv.z; t3 = tv.w;
    }
    float a0 = 0.f, a1 = 0.f, a2 = 0.f, a3 = 0.f;

#define GACC(v) { \
    float x0 = bf2f((v).x), x1 = bf2f((v).y), x2 = bf2f((v).z), x3 = bf2f((v).w); \
    if (AFFINE) { \
        x0 = fmaxf(fmaf(x0, s0, t0), 0.f); x1 = fmaxf(fmaf(x1, s1, t1), 0.f); \
        x2 = fmaxf(fmaf(x2, s2, t2), 0.f); x3 = fmaxf(fmaf(x3, s3, t3), 0.f); } \
    a0 += x0; a1 += x1; a2 += x2; a3 += x3; }

    short4 self = *(const short4*)&h16[(size_t)node * 128 + f4];
    GACC(self);

    const int beg = rowPtr[node], end = rowPtr[node + 1];
    int j = beg;
    for (; j + 8 <= end; j += 8) {
        int i0 = sortedSrc[j + 0], i1 = sortedSrc[j + 1];
        int i2 = sortedSrc[j + 2], i3 = sortedSrc[j + 3];
        int i4 = sortedSrc[j + 4], i5 = sortedSrc[j + 5];
        int i6 = sortedSrc[j + 6], i7 = sortedSrc[j + 7];
        short4 v0 = *(const short4*)&h16[(size_t)i0 * 128 + f4];
        short4 v1 = *(const short4*)&h16[(size_t)i1 * 128 + f4];
        short4 v2 = *(const short4*)&h16[(size_t)i2 * 128 + f4];
        short4 v3 = *(const short4*)&h16[(size_t)i3 * 128 + f4];
        short4 v4 = *(const short4*)&h16[(size_t)i4 * 128 + f4];
        short4 v5 = *(const short4*)&h16[(size_t)i5 * 128 + f4];
        short4 v6 = *(const short4*)&h16[(size_t)i6 * 128 + f4];
        short4 v7 = *(const short4*)&h16[(size_t)i7 * 128 + f4];
        GACC(v0); GACC(v1); GACC(v2); GACC(v3);
        GACC(v4); GACC(v5); GACC(v6); GACC(v7);
    }
    for (; j + 4 <= end; j += 4) {
        int i0 = sortedSrc[j], i1 = sortedSrc[j + 1], i2 = sortedSrc[j + 2], i3 = sortedSrc[j + 3];
        short4 v0 = *(const short4*)&h16[(size_t)i0 * 128 + f4];
        short4 v1 = *(const short4*)&h16[(size_t)i1 * 128 + f4];
        short4 v2 = *(const short4*)&h16[(size_t)i2 * 128 + f4];
        short4 v3 = *(const short4*)&h16[(size_t)i3 * 128 + f4];
        GACC(v0); GACC(v1); GACC(v2); GACC(v3);
    }
    for (; j < end; j++) {
        int ii = sortedSrc[j];
        short4 v = *(const short4*)&h16[(size_t)ii * 128 + f4];
        GACC(v);
    }
#undef GACC

    short4 o = {f2bf(a0), f2bf(a1), f2bf(a2), f2bf(a3)};
    *(short4*)&B16[(size_t)node * 128 + f4] = o;
}

// ---------------- fused per-layer MLP with W-prefetch, partial stats ----------------
// 256 threads, BM=64. In-place LDS chaining (wave-exclusive rows, validated R12).
// Phase ph: [barrier: sW(ph) ready] -> issue global loads of W(ph+1) into regs ->
// MFMA over sW(ph) -> epilogue -> [barrier: all done reading sW] -> ds_write regs -> loop.
__global__ __launch_bounds__(256) void mlp_layer_k(const short* __restrict__ B16,
                                                   const short* __restrict__ Wt0,
                                                   const short* __restrict__ Wt1,
                                                   const short* __restrict__ Wt2,
                                                   const float* __restrict__ b0,
                                                   const float* __restrict__ b1,
                                                   const float* __restrict__ b2,
                                                   short* __restrict__ Z16,
                                                   float* __restrict__ partial, int N) {
    constexpr int LR = 136;
    __shared__ __align__(16) short sA[64 * LR];
    __shared__ __align__(16) short sW[128 * LR];
    __shared__ float sStats[256];
    const int t = threadIdx.x;
    const int row0 = blockIdx.x * 64;
    const int w = t >> 6, l = t & 63;
    const int lr = l & 15, lg = l >> 4;

    sStats[t] = 0.f;
    for (int i = t; i < 64 * 16; i += 256) {
        int r = i >> 4, k0 = (i & 15) << 3;
        int gr = row0 + r;
        bf16x8 v = {0, 0, 0, 0, 0, 0, 0, 0};
        if (gr < N) v = *(const bf16x8*)&B16[(size_t)gr * 128 + k0];
        *(bf16x8*)&sA[r * LR + k0] = v;
    }
    for (int i = t; i < 128 * 16; i += 256) {
        int n = i >> 4, k0 = (i & 15) << 3;
        *(bf16x8*)&sW[n * LR + k0] = *(const bf16x8*)&Wt0[n * 128 + k0];
    }

    const short* Wnext[2] = {Wt1, Wt2};
    const float* bs[3] = {b0, b1, b2};
    bf16x8 wpre[8];

    for (int ph = 0; ph < 3; ph++) {
        __syncthreads();                       // sW(ph) and sA ready
        if (ph < 2) {
            const short* Wn = Wnext[ph];
#pragma unroll
            for (int q = 0; q < 8; q++) {
                int i = t + q * 256;           // [0, 2048)
                int n = i >> 4, k0 = (i & 15) << 3;
                wpre[q] = *(const bf16x8*)&Wn[n * 128 + k0];
            }
        }

        bf16x8 af[4];
#pragma unroll
        for (int kb = 0; kb < 4; kb++)
            af[kb] = *(const bf16x8*)&sA[(w * 16 + lr) * LR + kb * 32 + lg * 8];

        f32x4 acc[8];
#pragma unroll
        for (int n = 0; n < 8; n++) acc[n] = {0.f, 0.f, 0.f, 0.f};
#pragma unroll
        for (int n = 0; n < 8; n++)
#pragma unroll
            for (int kb = 0; kb < 4; kb++) {
                bf16x8 bf = *(const bf16x8*)&sW[(n * 16 + lr) * LR + kb * 32 + lg * 8];
                acc[n] = __builtin_amdgcn_mfma_f32_16x16x32_bf16(af[kb], bf, acc[n], 0, 0, 0);
            }

        const float* bias = bs[ph];
        if (ph < 2) {
#pragma unroll
            for (int n = 0; n < 8; n++) {
                const int col = n * 16 + lr;
                const float bv = bias[col];
#pragma unroll
                for (int j = 0; j < 4; j++) {
                    int rloc = w * 16 + lg * 4 + j;
                    float v = fmaxf(acc[n][j] + bv, 0.f);
                    sA[rloc * LR + col] = f2bf(v);
                }
            }
        } else {
#pragma unroll
            for (int n = 0; n < 8; n++) {
                const int col = n * 16 + lr;
                const float bv = bias[col];
                float part = 0.f, part2 = 0.f;
#pragma unroll
                for (int j = 0; j < 4; j++) {
                    int r = row0 + w * 16 + lg * 4 + j;
                    if (r < N) {
                        float v = acc[n][j] + bv;
                        Z16[(size_t)r * 128 + col] = f2bf(v);
                        part += v; part2 += v * v;
                    }
                }
                atomicAdd(&sStats[col], part);
                atomicAdd(&sStats[128 + col], part2);
            }
        }
        __syncthreads();                       // all waves done reading sW(ph)
        if (ph < 2) {
#pragma unroll
            for (int q = 0; q < 8; q++) {
                int i = t + q * 256;
                int n = i >> 4, k0 = (i & 15) << 3;
                *(bf16x8*)&sW[n * LR + k0] = wpre[q];
            }
        }
    }
    __syncthreads();                           // sStats complete
    partial[(size_t)blockIdx.x * 256 + t] = sStats[t];   // coalesced, NO global atomics
}

// ---------------- fused final (unchanged, validated) ----------------
__global__ __launch_bounds__(256) void fuse3_k(const short* __restrict__ Z0,
                                               const short* __restrict__ Z1,
                                               const short* __restrict__ Z2,
                                               const float* __restrict__ sb,
                                               const short* __restrict__ Wt,
                                               const float* __restrict__ linB,
                                               const float* __restrict__ clsB,
                                               float* __restrict__ hout,
                                               float* __restrict__ logits, int N) {
    constexpr int LR = 136;
    __shared__ __align__(16) short sA[64 * LR];
    __shared__ __align__(16) short sW[128 * LR];
    __shared__ __align__(16) short sH[64 * LR];
    const int t = threadIdx.x;
    const int row0 = blockIdx.x * 64;
    const int w = t >> 6, l = t & 63;
    const int lr = l & 15, lg = l >> 4;

    const short* Zs[3] = {Z0, Z1, Z2};

    f32x4 acc[8];
#pragma unroll
    for (int n = 0; n < 8; n++) acc[n] = {0.f, 0.f, 0.f, 0.f};

    for (int s = 0; s < 3; s++) {
        const short* Zsrc = Zs[s];
        const short* Wsrc = Wt + (size_t)(9 + s) * 16384;
        const float* ss = sb + (size_t)s * 256;
        const float* tt = ss + 128;
        for (int i = t; i < 128 * 16; i += 256) {
            int n = i >> 4, k0 = (i & 15) << 3;
            *(bf16x8*)&sW[n * LR + k0] = *(const bf16x8*)&Wsrc[n * 128 + k0];
        }
        for (int i = t; i < 64 * 16; i += 256) {
            int r = i >> 4, k0 = (i & 15) << 3;
            int gr = row0 + r;
            bf16x8 v = {0, 0, 0, 0, 0, 0, 0, 0};
            if (gr < N) {
                bf16x8 z = *(const bf16x8*)&Zsrc[(size_t)gr * 128 + k0];
#pragma unroll
                for (int e = 0; e < 8; e++) {
                    float xv = fmaf(bf2f(z[e]), ss[k0 + e], tt[k0 + e]);
                    if (s < 2) xv = fmaxf(xv, 0.f);
                    v[e] = f2bf(xv);
                }
            }
            *(bf16x8*)&sA[r * LR + k0] = v;
        }
        __syncthreads();
        bf16x8 af[4];
#pragma unroll
        for (int kb = 0; kb < 4; kb++)
            af[kb] = *(const bf16x8*)&sA[(w * 16 + lr) * LR + kb * 32 + lg * 8];
#pragma unroll
        for (int n = 0; n < 8; n++)
#pragma unroll
            for (int kb = 0; kb < 4; kb++) {
                bf16x8 bf = *(const bf16x8*)&sW[(n * 16 + lr) * LR + kb * 32 + lg * 8];
                acc[n] = __builtin_amdgcn_mfma_f32_16x16x32_bf16(af[kb], bf, acc[n], 0, 0, 0);
            }
        __syncthreads();
    }

#pragma unroll
    for (int n = 0; n < 8; n++) {
        const int col = n * 16 + lr;
        const float bv = linB[col];
#pragma unroll
        for (int j = 0; j < 4; j++) {
            int rloc = w * 16 + lg * 4 + j;
            int r = row0 + rloc;
            float v = acc[n][j] + bv;
            if (r < N) hout[(size_t)r * 128 + col] = v;
            sH[rloc * LR + col] = f2bf(v);
        }
    }
    for (int i = t; i < 64 * 16; i += 256) {
        int n = i >> 4, k0 = (i & 15) << 3;
        *(bf16x8*)&sW[n * LR + k0] = *(const bf16x8*)&Wt[(size_t)12 * 16384 + n * 128 + k0];
    }
    __syncthreads();

    bf16x8 ah[4];
#pragma unroll
    for (int kb = 0; kb < 4; kb++)
        ah[kb] = *(const bf16x8*)&sH[(w * 16 + lr) * LR + kb * 32 + lg * 8];

    f32x4 acc2[4];
#pragma unroll
    for (int n = 0; n < 4; n++) acc2[n] = {0.f, 0.f, 0.f, 0.f};
#pragma unroll
    for (int n = 0; n < 4; n++)
#pragma unroll
        for (int kb = 0; kb < 4; kb++) {
            bf16x8 bf = *(const bf16x8*)&sW[(n * 16 + lr) * LR + kb * 32 + lg * 8];
            acc2[n] = __builtin_amdgcn_mfma_f32_16x16x32_bf16(ah[kb], bf, acc2[n], 0, 0, 0);
        }
#pragma unroll
    for (int n = 0; n < 4; n++) {
        const int col = n * 16 + lr;
        const float bv = clsB[col];
#pragma unroll
        for (int j = 0; j < 4; j++) {
            int r = row0 + w * 16 + lg * 4 + j;
            if (r < N) logits[(size_t)r * 64 + col] = acc2[n][j] + bv;
        }
    }
}

// ---------------- launch ----------------

extern "C" void kernel_launch(void* const* d_in, const int* in_sizes, int n_in,
                              void* d_out, int out_size, void* d_ws, size_t ws_size,
                              hipStream_t stream) {
    const float* x     = (const float*)d_in[0];
    const int*   ei    = (const int*)d_in[1];
    const float* convW = (const float*)d_in[2];
    const float* convB = (const float*)d_in[3];
    const float* gamma = (const float*)d_in[4];
    const float* beta  = (const float*)d_in[5];
    const float* linW  = (const float*)d_in[6];
    const float* linB  = (const float*)d_in[7];
    const float* clsW  = (const float*)d_in[8];
    const float* clsB  = (const float*)d_in[9];

    const int N = in_sizes[0] / 128;   // 50000
    const int E = in_sizes[1] / 2;     // 800000
    const int* src = ei;
    const int* dst = ei + E;

    const int nbm = (N + 63) / 64;     // 782

    short* x16 = (short*)d_ws;                       // N*128
    short* B16 = x16 + (size_t)N * 128;              // N*128
    short* Z16 = B16 + (size_t)N * 128;              // 3 x N*128
    float* stats = (float*)(Z16 + (size_t)3 * N * 128);  // 768
    float* sb    = stats + 768;                      // 768
    float* partial = sb + 768;                       // nbm*256
    int* deg       = (int*)(partial + (size_t)nbm * 256);
    int* rowPtr    = deg + N;
    int* cursor    = rowPtr + (N + 1);
    int* chunkSum  = cursor + N;
    int* sortedSrc = chunkSum + 512;
    short* Wt = (short*)((((uintptr_t)(sortedSrc + E)) + 15) & ~(uintptr_t)15);

    float* logits = (float*)d_out;
    float* hout   = (float*)d_out + (size_t)N * 64;

    const int nchunks = (N + 511) / 512;
    const int eb = (E + 255) / 256;

    // ---- CSR build ----
    zero_int_k<<<(N + 255) / 256, 256, 0, stream>>>(deg, N);
    deg_count_k<<<eb, 256, 0, stream>>>(dst, deg, E);
    chunk_reduce_k<<<nchunks, 512, 0, stream>>>(deg, chunkSum, N);
    scan_chunks_k<<<1, 64, 0, stream>>>(chunkSum, rowPtr, nchunks, N);
    expand_scan_k<<<nchunks, 512, 0, stream>>>(deg, chunkSum, rowPtr, cursor, N);
    fill_k<<<eb, 256, 0, stream>>>(src, dst, cursor, sortedSrc, E);

    transpose_w_k<<<13, 256, 0, stream>>>(convW, linW, clsW, Wt);
    cast16_k<<<1024, 256, 0, stream>>>(x, x16, N * 32);
    zero_f_k<<<3, 256, 0, stream>>>(stats, 768);

    const int aggb = (N + 7) / 8;
    const int rb = (nbm + 15) / 16;    // 49

    for (int li = 0; li < 3; li++) {
        const short* hin16 = (li == 0) ? x16 : (Z16 + (size_t)(li - 1) * N * 128);
        const float* sbl   = sb + (size_t)(li - 1) * 256;
        if (li == 0)
            agg16_k<false><<<aggb, 256, 0, stream>>>(hin16, sortedSrc, rowPtr, nullptr, B16, N);
        else
            agg16_k<true><<<aggb, 256, 0, stream>>>(hin16, sortedSrc, rowPtr, sbl, B16, N);

        const short* Wt0 = Wt + (size_t)(li * 3 + 0) * 16384;
        const short* Wt1 = Wt + (size_t)(li * 3 + 1) * 16384;
        const short* Wt2 = Wt + (size_t)(li * 3 + 2) * 16384;
        const float* b0 = convB + ((size_t)li * 3 + 0) * 128;
        const float* b1 = convB + ((size_t)li * 3 + 1) * 128;
        const float* b2 = convB + ((size_t)li * 3 + 2) * 128;
        float* statL = stats + (size_t)li * 256;

        mlp_layer_k<<<nbm, 256, 0, stream>>>(B16, Wt0, Wt1, Wt2, b0, b1, b2,
                                             Z16 + (size_t)li * N * 128, partial, N);
        stats_reduce_k<<<rb, 256, 0, stream>>>(partial, statL, nbm);
        bnparam_k<<<1, 128, 0, stream>>>(statL, gamma + li * 128, beta + li * 128,
                                         sb + (size_t)li * 256, N);
    }

    fuse3_k<<<nbm, 256, 0, stream>>>(Z16, Z16 + (size_t)N * 128, Z16 + (size_t)2 * N * 128,
                                     sb, Wt, linB, clsB, hout, logits, N);
}

// Round 14
// 419.727 us; speedup vs baseline: 3.4974x; 1.1461x over previous
//
#include <hip/hip_runtime.h>
#include <hip/hip_bf16.h>
#include <stdint.h>

// GIN 3-layer forward on MI355X. Round 14:
//  - mlp_layer_k: phase-2 acc -> LDS -> COALESCED bf16x8 Z16 stores; stats recomputed
//    from LDS (no atomics); 3 phases straight-lined (no runtime-indexed ptr arrays).
//  - fuse3_k: h epilogue via LDS fp32 (reused sW) -> coalesced float4 hout stores;
//    clsW staged into freed sA; 3 lin steps straight-lined.
//  - agg16/CSR/transpose/cast/stats_reduce/bnparam unchanged (validated R13).

using bf16x8 = __attribute__((ext_vector_type(8))) short;
using f32x4  = __attribute__((ext_vector_type(4))) float;

__device__ inline short f2bf(float f) {
    union { __hip_bfloat16 h; short s; } u;
    u.h = __float2bfloat16(f);
    return u.s;
}
__device__ inline float bf2f(short s) {
    union { uint32_t u; float f; } c;
    c.u = ((uint32_t)(uint16_t)s) << 16;
    return c.f;
}

// ---------------- CSR build (unchanged, validated) ----------------

__global__ void zero_int_k(int* __restrict__ p, int n) {
    int i = blockIdx.x * blockDim.x + threadIdx.x;
    if (i < n) p[i] = 0;
}

__global__ void deg_count_k(const int* __restrict__ dst, int* __restrict__ deg, int E) {
    int e = blockIdx.x * blockDim.x + threadIdx.x;
    if (e < E) atomicAdd(&deg[dst[e]], 1);
}

__global__ __launch_bounds__(512) void chunk_reduce_k(const int* __restrict__ deg,
                                                      int* __restrict__ chunkSum, int N) {
    __shared__ int s[512];
    int i = blockIdx.x * 512 + threadIdx.x;
    s[threadIdx.x] = (i < N) ? deg[i] : 0;
    __syncthreads();
    for (int off = 256; off > 0; off >>= 1) {
        if (threadIdx.x < off) s[threadIdx.x] += s[threadIdx.x + off];
        __syncthreads();
    }
    if (threadIdx.x == 0) chunkSum[blockIdx.x] = s[0];
}

__global__ void scan_chunks_k(int* __restrict__ chunkSum, int* __restrict__ rowPtr,
                              int nchunks, int N) {
    if (threadIdx.x == 0 && blockIdx.x == 0) {
        int run = 0;
        for (int b = 0; b < nchunks; b++) {
            int v = chunkSum[b];
            chunkSum[b] = run;
            run += v;
        }
        rowPtr[N] = run;
    }
}

__global__ __launch_bounds__(512) void expand_scan_k(const int* __restrict__ deg,
                                                     const int* __restrict__ chunkOff,
                                                     int* __restrict__ rowPtr,
                                                     int* __restrict__ cursor, int N) {
    __shared__ int s[512];
    const int t = threadIdx.x;
    const int i = blockIdx.x * 512 + t;
    const int v = (i < N) ? deg[i] : 0;
    s[t] = v;
    __syncthreads();
    for (int off = 1; off < 512; off <<= 1) {
        int u = (t >= off) ? s[t - off] : 0;
        __syncthreads();
        s[t] += u;
        __syncthreads();
    }
    if (i < N) {
        int excl = s[t] - v + chunkOff[blockIdx.x];
        rowPtr[i] = excl;
        cursor[i] = excl;
    }
}

__global__ void fill_k(const int* __restrict__ src, const int* __restrict__ dst,
                       int* __restrict__ cursor, int* __restrict__ sortedSrc, int E) {
    int e = blockIdx.x * blockDim.x + threadIdx.x;
    if (e < E) {
        int pos = atomicAdd(&cursor[dst[e]], 1);
        sortedSrc[pos] = src[e];
    }
}

// ---------------- weight transpose + fp32->bf16 (unchanged, validated) ----------------
__global__ __launch_bounds__(256) void transpose_w_k(const float* __restrict__ convW,
                                                     const float* __restrict__ linW,
                                                     const float* __restrict__ clsW,
                                                     short* __restrict__ Wt) {
    const int b = blockIdx.x;
    const float* src;
    int NC;
    if (b < 9)       { src = convW + (size_t)b * 16384;      NC = 128; }
    else if (b < 12) { src = linW + (size_t)(b - 9) * 16384; NC = 128; }
    else             { src = clsW;                            NC = 64; }
    short* dst = Wt + (size_t)b * 16384;
    const int tot = NC * 32;
    for (int i = threadIdx.x; i < tot; i += 256) {
        int n = i >> 5, k0 = (i & 31) << 2;
        short4 s;
        s.x = f2bf(src[(k0 + 0) * NC + n]);
        s.y = f2bf(src[(k0 + 1) * NC + n]);
        s.z = f2bf(src[(k0 + 2) * NC + n]);
        s.w = f2bf(src[(k0 + 3) * NC + n]);
        *(short4*)&dst[n * 128 + k0] = s;
    }
}

__global__ void cast16_k(const float* __restrict__ x, short* __restrict__ x16, int n4) {
    int i = blockIdx.x * blockDim.x + threadIdx.x;
    int stride = gridDim.x * blockDim.x;
    for (; i < n4; i += stride) {
        float4 v = ((const float4*)x)[i];
        short4 s = {f2bf(v.x), f2bf(v.y), f2bf(v.z), f2bf(v.w)};
        ((short4*)x16)[i] = s;
    }
}

__global__ void zero_f_k(float* __restrict__ p, int n) {
    int i = blockIdx.x * blockDim.x + threadIdx.x;
    if (i < n) p[i] = 0.f;
}

// ---------------- partial-stats reduction (unchanged) ----------------
__global__ __launch_bounds__(256) void stats_reduce_k(const float* __restrict__ partial,
                                                      float* __restrict__ stats, int nb) {
    const int c = threadIdx.x;
    const int b0 = blockIdx.x * 16;
    const int bend = min(nb, b0 + 16);
    float s = 0.f;
    for (int b = b0; b < bend; b++)
        s += partial[(size_t)b * 256 + c];
    atomicAdd(&stats[c], s);
}

// ---------------- BN -> affine params (unchanged) ----------------
__global__ void bnparam_k(const float* __restrict__ stats, const float* __restrict__ gamma,
                          const float* __restrict__ beta, float* __restrict__ sb, int N) {
    int c = threadIdx.x;   // 128
    float inv = 1.f / (float)N;
    float mean = stats[c] * inv;
    float var = stats[128 + c] * inv - mean * mean;
    float s = gamma[c] * rsqrtf(var + 1e-5f);
    sb[c] = s;
    sb[128 + c] = beta[c] - mean * s;
}

// ---------------- aggregation (unchanged, validated R13) ----------------
template <bool AFFINE>
__global__ __launch_bounds__(256) void agg16_k(const short* __restrict__ h16,
                                               const int* __restrict__ sortedSrc,
                                               const int* __restrict__ rowPtr,
                                               const float* __restrict__ sb,
                                               short* __restrict__ B16, int N) {
    const int node = blockIdx.x * 8 + (threadIdx.x >> 5);
    if (node >= N) return;
    const int f4 = (threadIdx.x & 31) << 2;
    float s0 = 1.f, s1 = 1.f, s2 = 1.f, s3 = 1.f, t0 = 0.f, t1 = 0.f, t2 = 0.f, t3 = 0.f;
    if (AFFINE) {
        float4 sv = *(const float4*)&sb[f4];
        float4 tv = *(const float4*)&sb[128 + f4];
        s0 = sv.x; s1 = sv.y; s2 = sv.z; s3 = sv.w;
        t0 = tv.x; t1 = tv.y; t2 = tv.z; t3 = tv.w;
    }
    float a0 = 0.f, a1 = 0.f, a2 = 0.f, a3 = 0.f;

#define GACC(v) { \
    float x0 = bf2f((v).x), x1 = bf2f((v).y), x2 = bf2f((v).z), x3 = bf2f((v).w); \
    if (AFFINE) { \
        x0 = fmaxf(fmaf(x0, s0, t0), 0.f); x1 = fmaxf(fmaf(x1, s1, t1), 0.f); \
        x2 = fmaxf(fmaf(x2, s2, t2), 0.f); x3 = fmaxf(fmaf(x3, s3, t3), 0.f); } \
    a0 += x0; a1 += x1; a2 += x2; a3 += x3; }

    short4 self = *(const short4*)&h16[(size_t)node * 128 + f4];
    GACC(self);

    const int beg = rowPtr[node], end = rowPtr[node + 1];
    int j = beg;
    for (; j + 8 <= end; j += 8) {
        int i0 = sortedSrc[j + 0], i1 = sortedSrc[j + 1];
        int i2 = sortedSrc[j + 2], i3 = sortedSrc[j + 3];
        int i4 = sortedSrc[j + 4], i5 = sortedSrc[j + 5];
        int i6 = sortedSrc[j + 6], i7 = sortedSrc[j + 7];
        short4 v0 = *(const short4*)&h16[(size_t)i0 * 128 + f4];
        short4 v1 = *(const short4*)&h16[(size_t)i1 * 128 + f4];
        short4 v2 = *(const short4*)&h16[(size_t)i2 * 128 + f4];
        short4 v3 = *(const short4*)&h16[(size_t)i3 * 128 + f4];
        short4 v4 = *(const short4*)&h16[(size_t)i4 * 128 + f4];
        short4 v5 = *(const short4*)&h16[(size_t)i5 * 128 + f4];
        short4 v6 = *(const short4*)&h16[(size_t)i6 * 128 + f4];
        short4 v7 = *(const short4*)&h16[(size_t)i7 * 128 + f4];
        GACC(v0); GACC(v1); GACC(v2); GACC(v3);
        GACC(v4); GACC(v5); GACC(v6); GACC(v7);
    }
    for (; j + 4 <= end; j += 4) {
        int i0 = sortedSrc[j], i1 = sortedSrc[j + 1], i2 = sortedSrc[j + 2], i3 = sortedSrc[j + 3];
        short4 v0 = *(const short4*)&h16[(size_t)i0 * 128 + f4];
        short4 v1 = *(const short4*)&h16[(size_t)i1 * 128 + f4];
        short4 v2 = *(const short4*)&h16[(size_t)i2 * 128 + f4];
        short4 v3 = *(const short4*)&h16[(size_t)i3 * 128 + f4];
        GACC(v0); GACC(v1); GACC(v2); GACC(v3);
    }
    for (; j < end; j++) {
        int ii = sortedSrc[j];
        short4 v = *(const short4*)&h16[(size_t)ii * 128 + f4];
        GACC(v);
    }
#undef GACC

    short4 o = {f2bf(a0), f2bf(a1), f2bf(a2), f2bf(a3)};
    *(short4*)&B16[(size_t)node * 128 + f4] = o;
}

// ---------------- fused per-layer MLP, coalesced epilogue, straight-lined ----------------
__global__ __launch_bounds__(256) void mlp_layer_k(const short* __restrict__ B16,
                                                   const short* __restrict__ Wt0,
                                                   const short* __restrict__ Wt1,
                                                   const short* __restrict__ Wt2,
                                                   const float* __restrict__ b0,
                                                   const float* __restrict__ b1,
                                                   const float* __restrict__ b2,
                                                   short* __restrict__ Z16,
                                                   float* __restrict__ partial, int N) {
    constexpr int LR = 136;
    __shared__ __align__(16) short sA[64 * LR];
    __shared__ __align__(16) short sW[128 * LR];
    __shared__ float sSum[256];   // [half*128 + c]
    __shared__ float sSq[256];
    const int t = threadIdx.x;
    const int row0 = blockIdx.x * 64;
    const int w = t >> 6, l = t & 63;
    const int lr = l & 15, lg = l >> 4;

    // stage A and W0
    for (int i = t; i < 64 * 16; i += 256) {
        int r = i >> 4, k0 = (i & 15) << 3;
        int gr = row0 + r;
        bf16x8 v = {0, 0, 0, 0, 0, 0, 0, 0};
        if (gr < N) v = *(const bf16x8*)&B16[(size_t)gr * 128 + k0];
        *(bf16x8*)&sA[r * LR + k0] = v;
    }
    for (int i = t; i < 128 * 16; i += 256) {
        int n = i >> 4, k0 = (i & 15) << 3;
        *(bf16x8*)&sW[n * LR + k0] = *(const bf16x8*)&Wt0[n * 128 + k0];
    }

    bf16x8 wpre[8];

#define MLP_COMPUTE(BIAS, RELU_OUT)                                                  \
    {                                                                                \
        bf16x8 af[4];                                                                \
        _Pragma("unroll")                                                            \
        for (int kb = 0; kb < 4; kb++)                                               \
            af[kb] = *(const bf16x8*)&sA[(w * 16 + lr) * LR + kb * 32 + lg * 8];     \
        f32x4 acc[8];                                                                \
        _Pragma("unroll")                                                            \
        for (int n = 0; n < 8; n++) acc[n] = {0.f, 0.f, 0.f, 0.f};                   \
        _Pragma("unroll")                                                            \
        for (int n = 0; n < 8; n++)                                                  \
            _Pragma("unroll")                                                        \
            for (int kb = 0; kb < 4; kb++) {                                         \
                bf16x8 bf = *(const bf16x8*)&sW[(n * 16 + lr) * LR + kb * 32 + lg * 8]; \
                acc[n] = __builtin_amdgcn_mfma_f32_16x16x32_bf16(af[kb], bf, acc[n], 0, 0, 0); \
            }                                                                        \
        _Pragma("unroll")                                                            \
        for (int n = 0; n < 8; n++) {                                                \
            const int col = n * 16 + lr;                                             \
            const float bv = (BIAS)[col];                                            \
            _Pragma("unroll")                                                        \
            for (int j = 0; j < 4; j++) {                                            \
                int rloc = w * 16 + lg * 4 + j;                                      \
                float v = acc[n][j] + bv;                                            \
                if (RELU_OUT) v = fmaxf(v, 0.f);                                     \
                sA[rloc * LR + col] = f2bf(v);                                       \
            }                                                                        \
        }                                                                            \
    }

#define MLP_SWAP_W()                                                                 \
    {                                                                                \
        _Pragma("unroll")                                                            \
        for (int q = 0; q < 8; q++) {                                                \
            int i = t + q * 256;                                                     \
            int n = i >> 4, k0 = (i & 15) << 3;                                      \
            *(bf16x8*)&sW[n * LR + k0] = wpre[q];                                    \
        }                                                                            \
    }

    __syncthreads();                 // sA + sW(W0) ready
    // prefetch W1
#pragma unroll
    for (int q = 0; q < 8; q++) {
        int i = t + q * 256;
        int n = i >> 4, k0 = (i & 15) << 3;
        wpre[q] = *(const bf16x8*)&Wt1[n * 128 + k0];
    }
    MLP_COMPUTE(b0, true)
    __syncthreads();                 // all done reading sW(W0), sA writes visible
    MLP_SWAP_W()
    __syncthreads();                 // sW(W1) visible
    // prefetch W2
#pragma unroll
    for (int q = 0; q < 8; q++) {
        int i = t + q * 256;
        int n = i >> 4, k0 = (i & 15) << 3;
        wpre[q] = *(const bf16x8*)&Wt2[n * 128 + k0];
    }
    MLP_COMPUTE(b1, true)
    __syncthreads();
    MLP_SWAP_W()
    __syncthreads();                 // sW(W2) visible
    MLP_COMPUTE(b2, false)           // final Z (bf16) now in sA
    __syncthreads();                 // sA final visible to all waves

#undef MLP_COMPUTE
#undef MLP_SWAP_W

    // coalesced Z16 store: 16B per lane
    for (int i = t; i < 64 * 16; i += 256) {
        int r = i >> 4, k0 = (i & 15) << 3;
        int gr = row0 + r;
        if (gr < N)
            *(bf16x8*)&Z16[(size_t)gr * 128 + k0] = *(const bf16x8*)&sA[r * LR + k0];
    }
    // stats from sA: thread (c, half) sums 32 rows
    {
        const int c = t & 127, half = t >> 7;
        float s = 0.f, s2 = 0.f;
        const int rbeg = half * 32;
#pragma unroll 8
        for (int r = rbeg; r < rbeg + 32; r++) {
            if (row0 + r < N) {
                float v = bf2f(sA[r * LR + c]);
                s += v; s2 += v * v;
            }
        }
        sSum[half * 128 + c] = s;
        sSq[half * 128 + c] = s2;
    }
    __syncthreads();
    // fold halves, coalesced partial store: [c]=sum, [128+c]=sumsq
    {
        float v;
        if (t < 128) v = sSum[t] + sSum[128 + t];
        else         v = sSq[t - 128] + sSq[t];
        partial[(size_t)blockIdx.x * 256 + t] = v;
    }
}

// ---------------- fused final, coalesced hout, straight-lined ----------------
__global__ __launch_bounds__(256) void fuse3_k(const short* __restrict__ Z0,
                                               const short* __restrict__ Z1,
                                               const short* __restrict__ Z2,
                                               const float* __restrict__ sb,
                                               const short* __restrict__ Wt,
                                               const float* __restrict__ linB,
                                               const float* __restrict__ clsB,
                                               float* __restrict__ hout,
                                               float* __restrict__ logits, int N) {
    constexpr int LR = 136;
    __shared__ __align__(16) short sA[64 * LR];
    __shared__ __align__(16) short sW[128 * LR];   // reused as fp32 h (pitch 132) in epilogue
    __shared__ __align__(16) short sH[64 * LR];
    const int t = threadIdx.x;
    const int row0 = blockIdx.x * 64;
    const int w = t >> 6, l = t & 63;
    const int lr = l & 15, lg = l >> 4;

    f32x4 acc[8];
#pragma unroll
    for (int n = 0; n < 8; n++) acc[n] = {0.f, 0.f, 0.f, 0.f};

#define FUSE_STEP(ZSRC, WSLOT, SOFF, RELU_IN)                                        \
    {                                                                                \
        const short* Wsrc = Wt + (size_t)(WSLOT) * 16384;                            \
        const float* ss = sb + (SOFF);                                               \
        const float* tt = ss + 128;                                                  \
        for (int i = t; i < 128 * 16; i += 256) {                                    \
            int n = i >> 4, k0 = (i & 15) << 3;                                      \
            *(bf16x8*)&sW[n * LR + k0] = *(const bf16x8*)&Wsrc[n * 128 + k0];        \
        }                                                                            \
        for (int i = t; i < 64 * 16; i += 256) {                                     \
            int r = i >> 4, k0 = (i & 15) << 3;                                      \
            int gr = row0 + r;                                                       \
            bf16x8 v = {0, 0, 0, 0, 0, 0, 0, 0};                                     \
            if (gr < N) {                                                            \
                bf16x8 z = *(const bf16x8*)&(ZSRC)[(size_t)gr * 128 + k0];           \
                _Pragma("unroll")                                                    \
                for (int e = 0; e < 8; e++) {                                        \
                    float xv = fmaf(bf2f(z[e]), ss[k0 + e], tt[k0 + e]);             \
                    if (RELU_IN) xv = fmaxf(xv, 0.f);                                \
                    v[e] = f2bf(xv);                                                 \
                }                                                                    \
            }                                                                        \
            *(bf16x8*)&sA[r * LR + k0] = v;                                          \
        }                                                                            \
        __syncthreads();                                                             \
        bf16x8 af[4];                                                                \
        _Pragma("unroll")                                                            \
        for (int kb = 0; kb < 4; kb++)                                               \
            af[kb] = *(const bf16x8*)&sA[(w * 16 + lr) * LR + kb * 32 + lg * 8];     \
        _Pragma("unroll")                                                            \
        for (int n = 0; n < 8; n++)                                                  \
            _Pragma("unroll")                                                        \
            for (int kb = 0; kb < 4; kb++) {                                         \
                bf16x8 bf = *(const bf16x8*)&sW[(n * 16 + lr) * LR + kb * 32 + lg * 8]; \
                acc[n] = __builtin_amdgcn_mfma_f32_16x16x32_bf16(af[kb], bf, acc[n], 0, 0, 0); \
            }                                                                        \
        __syncthreads();                                                             \
    }

    FUSE_STEP(Z0, 9, 0, true)
    FUSE_STEP(Z1, 10, 256, true)
    FUSE_STEP(Z2, 11, 512, false)
#undef FUSE_STEP

    // h epilogue: fp32 into reused sW (pitch 132), bf16 into sH
    float* sWf = (float*)sW;
#pragma unroll
    for (int n = 0; n < 8; n++) {
        const int col = n * 16 + lr;
        const float bv = linB[col];
#pragma unroll
        for (int j = 0; j < 4; j++) {
            int rloc = w * 16 + lg * 4 + j;
            float v = acc[n][j] + bv;
            sWf[rloc * 132 + col] = v;
            sH[rloc * LR + col] = f2bf(v);
        }
    }
    // stage clsW into freed sA
    for (int i = t; i < 64 * 16; i += 256) {
        int n = i >> 4, k0 = (i & 15) << 3;
        *(bf16x8*)&sA[n * LR + k0] = *(const bf16x8*)&Wt[(size_t)12 * 16384 + n * 128 + k0];
    }
    __syncthreads();

    // coalesced hout store: float4 per lane
    for (int i = t; i < 64 * 32; i += 256) {
        int r = i >> 5, c4 = (i & 31) << 2;
        int gr = row0 + r;
        if (gr < N)
            *(float4*)&hout[(size_t)gr * 128 + c4] = *(const float4*)&sWf[r * 132 + c4];
    }

    // cls GEMM: ah from sH, weights from sA
    bf16x8 ah[4];
#pragma unroll
    for (int kb = 0; kb < 4; kb++)
        ah[kb] = *(const bf16x8*)&sH[(w * 16 + lr) * LR + kb * 32 + lg * 8];

    f32x4 acc2[4];
#pragma unroll
    for (int n = 0; n < 4; n++) acc2[n] = {0.f, 0.f, 0.f, 0.f};
#pragma unroll
    for (int n = 0; n < 4; n++)
#pragma unroll
        for (int kb = 0; kb < 4; kb++) {
            bf16x8 bf = *(const bf16x8*)&sA[(n * 16 + lr) * LR + kb * 32 + lg * 8];
            acc2[n] = __builtin_amdgcn_mfma_f32_16x16x32_bf16(ah[kb], bf, acc2[n], 0, 0, 0);
        }
#pragma unroll
    for (int n = 0; n < 4; n++) {
        const int col = n * 16 + lr;
        const float bv = clsB[col];
#pragma unroll
        for (int j = 0; j < 4; j++) {
            int r = row0 + w * 16 + lg * 4 + j;
            if (r < N) logits[(size_t)r * 64 + col] = acc2[n][j] + bv;
        }
    }
}

// ---------------- launch ----------------

extern "C" void kernel_launch(void* const* d_in, const int* in_sizes, int n_in,
                              void* d_out, int out_size, void* d_ws, size_t ws_size,
                              hipStream_t stream) {
    const float* x     = (const float*)d_in[0];
    const int*   ei    = (const int*)d_in[1];
    const float* convW = (const float*)d_in[2];
    const float* convB = (const float*)d_in[3];
    const float* gamma = (const float*)d_in[4];
    const float* beta  = (const float*)d_in[5];
    const float* linW  = (const float*)d_in[6];
    const float* linB  = (const float*)d_in[7];
    const float* clsW  = (const float*)d_in[8];
    const float* clsB  = (const float*)d_in[9];

    const int N = in_sizes[0] / 128;   // 50000
    const int E = in_sizes[1] / 2;     // 800000
    const int* src = ei;
    const int* dst = ei + E;

    const int nbm = (N + 63) / 64;     // 782

    short* x16 = (short*)d_ws;                       // N*128
    short* B16 = x16 + (size_t)N * 128;              // N*128
    short* Z16 = B16 + (size_t)N * 128;              // 3 x N*128
    float* stats = (float*)(Z16 + (size_t)3 * N * 128);  // 768
    float* sb    = stats + 768;                      // 768
    float* partial = sb + 768;                       // nbm*256
    int* deg       = (int*)(partial + (size_t)nbm * 256);
    int* rowPtr    = deg + N;
    int* cursor    = rowPtr + (N + 1);
    int* chunkSum  = cursor + N;
    int* sortedSrc = chunkSum + 512;
    short* Wt = (short*)((((uintptr_t)(sortedSrc + E)) + 15) & ~(uintptr_t)15);

    float* logits = (float*)d_out;
    float* hout   = (float*)d_out + (size_t)N * 64;

    const int nchunks = (N + 511) / 512;
    const int eb = (E + 255) / 256;

    // ---- CSR build ----
    zero_int_k<<<(N + 255) / 256, 256, 0, stream>>>(deg, N);
    deg_count_k<<<eb, 256, 0, stream>>>(dst, deg, E);
    chunk_reduce_k<<<nchunks, 512, 0, stream>>>(deg, chunkSum, N);
    scan_chunks_k<<<1, 64, 0, stream>>>(chunkSum, rowPtr, nchunks, N);
    expand_scan_k<<<nchunks, 512, 0, stream>>>(deg, chunkSum, rowPtr, cursor, N);
    fill_k<<<eb, 256, 0, stream>>>(src, dst, cursor, sortedSrc, E);

    transpose_w_k<<<13, 256, 0, stream>>>(convW, linW, clsW, Wt);
    cast16_k<<<1024, 256, 0, stream>>>(x, x16, N * 32);
    zero_f_k<<<3, 256, 0, stream>>>(stats, 768);

    const int aggb = (N + 7) / 8;
    const int rb = (nbm + 15) / 16;    // 49

    for (int li = 0; li < 3; li++) {
        const short* hin16 = (li == 0) ? x16 : (Z16 + (size_t)(li - 1) * N * 128);
        const float* sbl   = sb + (size_t)(li - 1) * 256;
        if (li == 0)
            agg16_k<false><<<aggb, 256, 0, stream>>>(hin16, sortedSrc, rowPtr, nullptr, B16, N);
        else
            agg16_k<true><<<aggb, 256, 0, stream>>>(hin16, sortedSrc, rowPtr, sbl, B16, N);

        const short* Wt0 = Wt + (size_t)(li * 3 + 0) * 16384;
        const short* Wt1 = Wt + (size_t)(li * 3 + 1) * 16384;
        const short* Wt2 = Wt + (size_t)(li * 3 + 2) * 16384;
        const float* b0 = convB + ((size_t)li * 3 + 0) * 128;
        const float* b1 = convB + ((size_t)li * 3 + 1) * 128;
        const float* b2 = convB + ((size_t)li * 3 + 2) * 128;
        float* statL = stats + (size_t)li * 256;

        mlp_layer_k<<<nbm, 256, 0, stream>>>(B16, Wt0, Wt1, Wt2, b0, b1, b2,
                                             Z16 + (size_t)li * N * 128, partial, N);
        stats_reduce_k<<<rb, 256, 0, stream>>>(partial, statL, nbm);
        bnparam_k<<<1, 128, 0, stream>>>(statL, gamma + li * 128, beta + li * 128,
                                         sb + (size_t)li * 256, N);
    }

    fuse3_k<<<nbm, 256, 0, stream>>>(Z16, Z16 + (size_t)N * 128, Z16 + (size_t)2 * N * 128,
                                     sb, Wt, linB, clsB, hout, logits, N);
}